// Round 2
// baseline (3386.553 us; speedup 1.0000x reference)
//
#include <hip/hip_runtime.h>
#include <math.h>

#define THRESH_C 0.05f
#define COEF_C   0.01f

typedef __bf16 bf16;
typedef __bf16 bf16x8 __attribute__((ext_vector_type(8)));
typedef __bf16 bf16x4 __attribute__((ext_vector_type(4)));
typedef float  f32x4  __attribute__((ext_vector_type(4)));

// ---------------- f32 -> split (hi+lo bf16) ----------------
__global__ __launch_bounds__(256) void k_f32_to_split(const float* __restrict__ in,
                                                      bf16* __restrict__ hi,
                                                      bf16* __restrict__ lo, long n) {
    long i = ((long)blockIdx.x * 256 + threadIdx.x) * 4;
    if (i >= n) return;
    float4 v = *(const float4*)(in + i);
    bf16x4 h, l;
    h[0] = (bf16)v.x; l[0] = (bf16)(v.x - (float)h[0]);
    h[1] = (bf16)v.y; l[1] = (bf16)(v.y - (float)h[1]);
    h[2] = (bf16)v.z; l[2] = (bf16)(v.z - (float)h[2]);
    h[3] = (bf16)v.w; l[3] = (bf16)(v.w - (float)h[3]);
    *(bf16x4*)(hi + i) = h;
    *(bf16x4*)(lo + i) = l;
}

// ---------------- f32 transpose -> split ----------------
__global__ __launch_bounds__(256) void k_transpose_f32_split(const float* __restrict__ in,
                                                             bf16* __restrict__ oh,
                                                             bf16* __restrict__ ol,
                                                             int R, int C) {
    __shared__ float t[64][65];
    int r0 = blockIdx.y * 64, c0 = blockIdx.x * 64;
    for (int i = threadIdx.x; i < 4096; i += 256) {
        int r = i >> 6, c = i & 63;
        t[r][c] = in[(long)(r0 + r) * C + (c0 + c)];
    }
    __syncthreads();
    for (int i = threadIdx.x; i < 4096; i += 256) {
        int c = i >> 6, r = i & 63;
        float v = t[r][c];
        bf16 h = (bf16)v;
        long o = (long)(c0 + c) * R + (r0 + r);
        oh[o] = h;
        ol[o] = (bf16)(v - (float)h);
    }
}

// ---------------- generic transpose to bf16 (single) ----------------
template<typename Tin>
__global__ __launch_bounds__(256) void k_transpose_to_bf16(const Tin* __restrict__ in,
                                                           bf16* __restrict__ out,
                                                           int R, int C,
                                                           long inStride, long outStride) {
    __shared__ bf16 t[64][65];
    const Tin* ib = in + (long)blockIdx.z * inStride;
    bf16* ob = out + (long)blockIdx.z * outStride;
    int r0 = blockIdx.y * 64, c0 = blockIdx.x * 64;
    for (int i = threadIdx.x; i < 4096; i += 256) {
        int r = i >> 6, c = i & 63;
        t[r][c] = (bf16)(float)ib[(long)(r0 + r) * C + (c0 + c)];
    }
    __syncthreads();
    for (int i = threadIdx.x; i < 4096; i += 256) {
        int c = i >> 6, r = i & 63;
        ob[(long)(c0 + c) * R + (r0 + r)] = t[r][c];
    }
}

// ---------------- bias fold: y = b2 + W @ b1 (W [1024][1024] f32 row-major) ----------------
__global__ __launch_bounds__(256) void k_bias_fold(const float* __restrict__ W,
                                                   const float* __restrict__ b1,
                                                   const float* __restrict__ b2,
                                                   float* __restrict__ y) {
    int row = blockIdx.x * 4 + (threadIdx.x >> 6);
    int lane = threadIdx.x & 63;
    const float* wr = W + (long)row * 1024;
    float s = 0.f;
    for (int k = lane; k < 1024; k += 64) s += wr[k] * b1[k];
#pragma unroll
    for (int o = 32; o >= 1; o >>= 1) s += __shfl_xor(s, o);
    if (lane == 0) y[row] = b2[row] + s;
}

// ---------------- high-precision split-bf16 GEMM: C = alpha*(A @ B^T) + bias ----------------
// A = Ah+Al [M,K]; B = Bh+Bl [N,K]. acc = Ah*Bh + Ah*Bl + Al*Bh (f32 accum).
enum { HP_SPLIT = 0, HP_F32 = 1 };

template<int MODE>
__global__ __launch_bounds__(256)
void gemm_hp(const bf16* __restrict__ Ah, const bf16* __restrict__ Al, int lda, long sAz,
             const bf16* __restrict__ Bh, const bf16* __restrict__ Bl, int ldb, long sBz,
             void* __restrict__ Chv, bf16* __restrict__ Cl, int ldc, long sCz,
             const float* __restrict__ bias, float alpha, int M, int N, int K) {
    __shared__ alignas(16) bf16 sAh[128 * 32];
    __shared__ alignas(16) bf16 sAl[128 * 32];
    __shared__ alignas(16) bf16 sBh[128 * 32];
    __shared__ alignas(16) bf16 sBl[128 * 32];
    const int bm = blockIdx.y, bn = blockIdx.x, z = blockIdx.z;
    const bf16* Ahb = Ah + (long)z * sAz;
    const bf16* Alb = Al + (long)z * sAz;
    const bf16* Bhb = Bh + (long)z * sBz;
    const bf16* Blb = Bl + (long)z * sBz;
    const int tid  = threadIdx.x;
    const int lane = tid & 63, wave = tid >> 6;
    const int quad = lane >> 4, l16 = lane & 15;
    const int wr = wave >> 1, wc = wave & 1;
    const int sr = tid >> 2;
    const int sc = (tid & 3) * 8;

    int arow0 = min(bm * 128 + sr, M - 1);
    int arow1 = min(bm * 128 + sr + 64, M - 1);
    int brow0 = min(bn * 128 + sr, N - 1);
    int brow1 = min(bn * 128 + sr + 64, N - 1);

    f32x4 acc[4][4];
#pragma unroll
    for (int i = 0; i < 4; i++)
#pragma unroll
        for (int j = 0; j < 4; j++) acc[i][j] = (f32x4){0.f, 0.f, 0.f, 0.f};

    for (int k0 = 0; k0 < K; k0 += 32) {
        __syncthreads();
        *(f32x4*)&sAh[sr * 32 + sc]        = *(const f32x4*)(Ahb + (long)arow0 * lda + k0 + sc);
        *(f32x4*)&sAh[(sr + 64) * 32 + sc] = *(const f32x4*)(Ahb + (long)arow1 * lda + k0 + sc);
        *(f32x4*)&sAl[sr * 32 + sc]        = *(const f32x4*)(Alb + (long)arow0 * lda + k0 + sc);
        *(f32x4*)&sAl[(sr + 64) * 32 + sc] = *(const f32x4*)(Alb + (long)arow1 * lda + k0 + sc);
        *(f32x4*)&sBh[sr * 32 + sc]        = *(const f32x4*)(Bhb + (long)brow0 * ldb + k0 + sc);
        *(f32x4*)&sBh[(sr + 64) * 32 + sc] = *(const f32x4*)(Bhb + (long)brow1 * ldb + k0 + sc);
        *(f32x4*)&sBl[sr * 32 + sc]        = *(const f32x4*)(Blb + (long)brow0 * ldb + k0 + sc);
        *(f32x4*)&sBl[(sr + 64) * 32 + sc] = *(const f32x4*)(Blb + (long)brow1 * ldb + k0 + sc);
        __syncthreads();
        bf16x8 ah[4], al[4], bh[4], bl[4];
#pragma unroll
        for (int i = 0; i < 4; i++) {
            int ro = (wr * 64 + i * 16 + l16) * 32 + quad * 8;
            ah[i] = *(const bf16x8*)&sAh[ro];
            al[i] = *(const bf16x8*)&sAl[ro];
        }
#pragma unroll
        for (int j = 0; j < 4; j++) {
            int ro = (wc * 64 + j * 16 + l16) * 32 + quad * 8;
            bh[j] = *(const bf16x8*)&sBh[ro];
            bl[j] = *(const bf16x8*)&sBl[ro];
        }
#pragma unroll
        for (int i = 0; i < 4; i++)
#pragma unroll
            for (int j = 0; j < 4; j++) {
                acc[i][j] = __builtin_amdgcn_mfma_f32_16x16x32_bf16(al[i], bh[j], acc[i][j], 0, 0, 0);
                acc[i][j] = __builtin_amdgcn_mfma_f32_16x16x32_bf16(ah[i], bl[j], acc[i][j], 0, 0, 0);
                acc[i][j] = __builtin_amdgcn_mfma_f32_16x16x32_bf16(ah[i], bh[j], acc[i][j], 0, 0, 0);
            }
    }

#pragma unroll
    for (int i = 0; i < 4; i++) {
        int mbase = bm * 128 + wr * 64 + i * 16 + quad * 4;
#pragma unroll
        for (int j = 0; j < 4; j++) {
            int n = bn * 128 + wc * 64 + j * 16 + l16;
            if (n < N) {
                float bv = bias ? bias[n] : 0.f;
#pragma unroll
                for (int r = 0; r < 4; r++) {
                    int m = mbase + r;
                    if (m < M) {
                        float v = alpha * acc[i][j][r] + bv;
                        long cidx = (long)z * sCz + (long)m * ldc + n;
                        if (MODE == HP_SPLIT) {
                            bf16 h = (bf16)v;
                            ((bf16*)Chv)[cidx] = h;
                            Cl[cidx] = (bf16)(v - (float)h);
                        } else {
                            ((float*)Chv)[cidx] = v;
                        }
                    }
                }
            }
        }
    }
}

// ---------------- single-bf16 GEMM (MoE path) ----------------
enum { EPI_GELU_BF16 = 0, EPI_ACC_ROWSCALE = 1 };

template<int MODE>
__global__ __launch_bounds__(256)
void gemm_bt(const bf16* __restrict__ A, int lda,
             const bf16* __restrict__ B, int ldb,
             void* __restrict__ Cv, int ldc,
             const float* __restrict__ bias,
             const float* __restrict__ rowscale, int rsStride,
             int M, int N, int K) {
    __shared__ alignas(16) bf16 sA[128 * 32];
    __shared__ alignas(16) bf16 sB[128 * 32];
    const int bm = blockIdx.y, bn = blockIdx.x;
    const int tid  = threadIdx.x;
    const int lane = tid & 63, wave = tid >> 6;
    const int quad = lane >> 4, l16 = lane & 15;
    const int wr = wave >> 1, wc = wave & 1;
    const int sr = tid >> 2;
    const int sc = (tid & 3) * 8;

    int arow0 = min(bm * 128 + sr, M - 1);
    int arow1 = min(bm * 128 + sr + 64, M - 1);
    int brow0 = min(bn * 128 + sr, N - 1);
    int brow1 = min(bn * 128 + sr + 64, N - 1);

    f32x4 acc[4][4];
#pragma unroll
    for (int i = 0; i < 4; i++)
#pragma unroll
        for (int j = 0; j < 4; j++) acc[i][j] = (f32x4){0.f, 0.f, 0.f, 0.f};

    for (int k0 = 0; k0 < K; k0 += 32) {
        __syncthreads();
        *(f32x4*)&sA[sr * 32 + sc]        = *(const f32x4*)(A + (long)arow0 * lda + k0 + sc);
        *(f32x4*)&sA[(sr + 64) * 32 + sc] = *(const f32x4*)(A + (long)arow1 * lda + k0 + sc);
        *(f32x4*)&sB[sr * 32 + sc]        = *(const f32x4*)(B + (long)brow0 * ldb + k0 + sc);
        *(f32x4*)&sB[(sr + 64) * 32 + sc] = *(const f32x4*)(B + (long)brow1 * ldb + k0 + sc);
        __syncthreads();
        bf16x8 af[4], bfr[4];
#pragma unroll
        for (int i = 0; i < 4; i++)
            af[i] = *(const bf16x8*)&sA[(wr * 64 + i * 16 + l16) * 32 + quad * 8];
#pragma unroll
        for (int j = 0; j < 4; j++)
            bfr[j] = *(const bf16x8*)&sB[(wc * 64 + j * 16 + l16) * 32 + quad * 8];
#pragma unroll
        for (int i = 0; i < 4; i++)
#pragma unroll
            for (int j = 0; j < 4; j++)
                acc[i][j] = __builtin_amdgcn_mfma_f32_16x16x32_bf16(af[i], bfr[j], acc[i][j], 0, 0, 0);
    }

#pragma unroll
    for (int i = 0; i < 4; i++) {
        int mbase = bm * 128 + wr * 64 + i * 16 + quad * 4;
#pragma unroll
        for (int j = 0; j < 4; j++) {
            int n = bn * 128 + wc * 64 + j * 16 + l16;
            if (n < N) {
                float bv = bias ? bias[n] : 0.f;
#pragma unroll
                for (int r = 0; r < 4; r++) {
                    int m = mbase + r;
                    if (m < M) {
                        float v = acc[i][j][r] + bv;
                        long cidx = (long)m * ldc + n;
                        if (MODE == EPI_GELU_BF16) {
                            float g = 0.5f * v * (1.f + erff(v * 0.70710678118654752f));
                            ((bf16*)Cv)[cidx] = (bf16)g;
                        } else {
                            float s = rowscale[(long)m * rsStride];
                            if (s != 0.f) ((float*)Cv)[cidx] += s * v;
                        }
                    }
                }
            }
        }
    }
}

// ---------------- softmax rows (f32 in, split bf16 out) ----------------
__global__ __launch_bounds__(256) void k_softmax_split(const float* __restrict__ S,
                                                       bf16* __restrict__ Ph,
                                                       bf16* __restrict__ Pl) {
    int row = blockIdx.x * 4 + (threadIdx.x >> 6);
    int lane = threadIdx.x & 63;
    const float* p = S + (long)row * 1024 + lane * 16;
    float v[16];
#pragma unroll
    for (int i = 0; i < 16; i += 4) {
        f32x4 a = *(const f32x4*)(p + i);
        v[i] = a[0]; v[i + 1] = a[1]; v[i + 2] = a[2]; v[i + 3] = a[3];
    }
    float mx = v[0];
#pragma unroll
    for (int i = 1; i < 16; i++) mx = fmaxf(mx, v[i]);
#pragma unroll
    for (int o = 32; o >= 1; o >>= 1) mx = fmaxf(mx, __shfl_xor(mx, o));
    float s = 0.f;
#pragma unroll
    for (int i = 0; i < 16; i++) { v[i] = expf(v[i] - mx); s += v[i]; }
#pragma unroll
    for (int o = 32; o >= 1; o >>= 1) s += __shfl_xor(s, o);
    float inv = 1.f / s;
    bf16x8 h0, h1, l0, l1;
#pragma unroll
    for (int i = 0; i < 8; i++) {
        float a = v[i] * inv;
        h0[i] = (bf16)a; l0[i] = (bf16)(a - (float)h0[i]);
        float b = v[8 + i] * inv;
        h1[i] = (bf16)b; l1[i] = (bf16)(b - (float)h1[i]);
    }
    long o = (long)row * 1024 + lane * 16;
    *(bf16x8*)(Ph + o) = h0;  *(bf16x8*)(Ph + o + 8) = h1;
    *(bf16x8*)(Pl + o) = l0;  *(bf16x8*)(Pl + o + 8) = l1;
}

// ---------------- layernorm: out = LN(xin + resid)*g + b ----------------
__global__ __launch_bounds__(256) void k_ln(const float* __restrict__ xin,
                                            const float* __restrict__ resid,
                                            const float* __restrict__ g,
                                            const float* __restrict__ bb,
                                            float* __restrict__ outf,
                                            bf16* __restrict__ outb) {
    int row = blockIdx.x * 4 + (threadIdx.x >> 6);
    int lane = threadIdx.x & 63;
    long base = (long)row * 1024 + lane * 16;
    float v[16];
#pragma unroll
    for (int i = 0; i < 16; i += 4) {
        f32x4 a = *(const f32x4*)(xin + base + i);
        if (resid) { f32x4 r4 = *(const f32x4*)(resid + base + i); a += r4; }
        v[i] = a[0]; v[i + 1] = a[1]; v[i + 2] = a[2]; v[i + 3] = a[3];
    }
    float s = 0.f;
#pragma unroll
    for (int i = 0; i < 16; i++) s += v[i];
#pragma unroll
    for (int o = 32; o >= 1; o >>= 1) s += __shfl_xor(s, o);
    float mean = s * (1.f / 1024.f);
    float vs = 0.f;
#pragma unroll
    for (int i = 0; i < 16; i++) { float d = v[i] - mean; vs += d * d; }
#pragma unroll
    for (int o = 32; o >= 1; o >>= 1) vs += __shfl_xor(vs, o);
    float inv = 1.f / sqrtf(vs * (1.f / 1024.f) + 1e-5f);
    const float* gp = g + lane * 16;
    const float* bp = bb + lane * 16;
#pragma unroll
    for (int i = 0; i < 16; i++) {
        float o = (v[i] - mean) * inv * gp[i] + bp[i];
        if (outf) outf[base + i] = o;
        if (outb) outb[base + i] = (bf16)o;
    }
}

// ---------------- MoE gating ----------------
__global__ __launch_bounds__(256) void k_gate(const float* __restrict__ X,
                                              const float* __restrict__ Wg,
                                              float* __restrict__ combine,
                                              float* __restrict__ partials) {
    __shared__ float sm[16];
    if (threadIdx.x < 16) sm[threadIdx.x] = 0.f;
    __syncthreads();
    int t = blockIdx.x * 4 + (threadIdx.x >> 6);
    int lane = threadIdx.x & 63;
    const float* x = X + (long)t * 1024;
    float acc[8] = {0.f, 0.f, 0.f, 0.f, 0.f, 0.f, 0.f, 0.f};
    for (int i = lane; i < 1024; i += 64) {
        float xv = x[i];
        const float* w = Wg + i * 8;
#pragma unroll
        for (int e = 0; e < 8; e++) acc[e] += xv * w[e];
    }
#pragma unroll
    for (int e = 0; e < 8; e++)
#pragma unroll
        for (int o = 32; o >= 1; o >>= 1) acc[e] += __shfl_xor(acc[e], o);
    if (lane == 0) {
        float mx = acc[0];
#pragma unroll
        for (int e = 1; e < 8; e++) mx = fmaxf(mx, acc[e]);
        float p[8], s = 0.f;
#pragma unroll
        for (int e = 0; e < 8; e++) { p[e] = expf(acc[e] - mx); s += p[e]; }
        float invs = 1.f / s;
#pragma unroll
        for (int e = 0; e < 8; e++) p[e] *= invs;
        float b1 = -1.f, b2 = -1.f, b3 = -1.f; int i1 = 0, i2 = 0, i3 = 0;
#pragma unroll
        for (int e = 0; e < 8; e++) {
            float pe = p[e];
            if (pe > b1)      { b3 = b2; i3 = i2; b2 = b1; i2 = i1; b1 = pe; i1 = e; }
            else if (pe > b2) { b3 = b2; i3 = i2; b2 = pe; i2 = e; }
            else if (pe > b3) { b3 = pe; i3 = e; }
        }
        float c[8] = {0.f, 0.f, 0.f, 0.f, 0.f, 0.f, 0.f, 0.f};
        c[i1] = b1;
        if (b2 >= THRESH_C) c[i2] = b2;
        if (b3 >= THRESH_C) c[i3] = b3;
        float* co = combine + (long)t * 8;
#pragma unroll
        for (int e = 0; e < 8; e++) co[e] = c[e];
#pragma unroll
        for (int e = 0; e < 8; e++) {
            atomicAdd(&sm[e], p[e]);
            if (c[e] > 0.f) atomicAdd(&sm[8 + e], 1.f);
        }
    }
    __syncthreads();
    if (threadIdx.x < 16) partials[(long)blockIdx.x * 16 + threadIdx.x] = sm[threadIdx.x];
}

// ---------------- aux reduce ----------------
__global__ __launch_bounds__(256) void k_aux(const float* __restrict__ partials, int nblocks,
                                             float* __restrict__ auxout) {
    __shared__ float red[256];
    int tid = threadIdx.x;
    int e = tid & 15, grp = tid >> 4;
    float s = 0.f;
    for (int b = grp; b < nblocks; b += 16) s += partials[(long)b * 16 + e];
    red[tid] = s;
    __syncthreads();
    if (grp == 0) {
        float tot = 0.f;
        for (int g2 = 0; g2 < 16; g2++) tot += red[g2 * 16 + e];
        red[tid] = tot;
    }
    __syncthreads();
    if (tid == 0) {
        float s2 = 0.f;
        for (int e2 = 0; e2 < 8; e2++)
            s2 += (red[8 + e2] * (1.f / 4096.f)) * (red[e2] * (1.f / 4096.f));
        auxout[0] = COEF_C * 8.f * s2;
    }
}

// ---------------- host ----------------
extern "C" void kernel_launch(void* const* d_in, const int* in_sizes, int n_in,
                              void* d_out, int out_size, void* d_ws, size_t ws_size,
                              hipStream_t stream) {
    const float* query     = (const float*)d_in[0];
    const float* key_value = (const float*)d_in[1];
    const float* Wq   = (const float*)d_in[2];
    const float* bq   = (const float*)d_in[3];
    const float* Wk   = (const float*)d_in[4];
    const float* bk   = (const float*)d_in[5];
    const float* Wv   = (const float*)d_in[6];
    const float* bv   = (const float*)d_in[7];
    const float* W_in = (const float*)d_in[8];
    const float* b_in = (const float*)d_in[9];
    const float* W_out = (const float*)d_in[10];
    const float* b_out = (const float*)d_in[11];
    const float* Wa   = (const float*)d_in[12];
    const float* ba   = (const float*)d_in[13];
    const float* ln1_g = (const float*)d_in[14];
    const float* ln1_b = (const float*)d_in[15];
    const float* Wg   = (const float*)d_in[16];
    const float* ew1  = (const float*)d_in[17];
    const float* eb1  = (const float*)d_in[18];
    const float* ew2  = (const float*)d_in[19];
    const float* eb2  = (const float*)d_in[20];
    const float* ln2_g = (const float*)d_in[21];
    const float* ln2_b = (const float*)d_in[22];

    const size_t MBY = 1ull << 20;
    const long MB1 = 1024L * 1024L;   // 1M elements
    char* ws = (char*)d_ws;

    // ---- fixed regions ----
    bf16* ew1t = (bf16*)(ws + 0 * MBY);      // 64MB
    bf16* ew2t = (bf16*)(ws + 64 * MBY);     // 64MB
    char* R1   = ws + 128 * MBY;             // 64MB multi-phase region
    // phase A (prep)
    bf16* WqT_h = (bf16*)(R1 + 0 * MBY),  *WqT_l = (bf16*)(R1 + 2 * MBY);
    bf16* WkT_h = (bf16*)(R1 + 4 * MBY),  *WkT_l = (bf16*)(R1 + 6 * MBY);
    bf16* WvT_h = (bf16*)(R1 + 8 * MBY),  *WvT_l = (bf16*)(R1 + 10 * MBY);
    bf16* WoT_h = (bf16*)(R1 + 12 * MBY), *WoT_l = (bf16*)(R1 + 14 * MBY);
    bf16* Win_h = (bf16*)(R1 + 16 * MBY), *Win_l = (bf16*)(R1 + 22 * MBY);
    bf16* Wa_h  = (bf16*)(R1 + 28 * MBY), *Wa_l  = (bf16*)(R1 + 30 * MBY);
    bf16* Xq_h  = (bf16*)(R1 + 32 * MBY), *Xq_l  = (bf16*)(R1 + 40 * MBY);
    bf16* Xkv_h = (bf16*)(R1 + 48 * MBY), *Xkv_l = (bf16*)(R1 + 56 * MBY);
    // phase B (attention) — prep weights + Xq/Xkv dead by then
    float* S  = (float*)(R1 + 0 * MBY);      // 32MB (8 heads f32)
    bf16* Ph  = (bf16*)(R1 + 32 * MBY);      // 16MB
    bf16* Pl  = (bf16*)(R1 + 48 * MBY);      // 16MB
    // phase C (MoE) — S/P dead by then
    bf16* Hbuf     = (bf16*)(R1 + 0 * MBY);  // 32MB
    float* moe_out = (float*)(R1 + 32 * MBY);// 16MB
    // persistent
    bf16* Weq_h = (bf16*)(ws + 192 * MBY), *Weq_l = (bf16*)(ws + 194 * MBY);
    bf16* Wek_h = (bf16*)(ws + 196 * MBY), *Wek_l = (bf16*)(ws + 198 * MBY);
    bf16* Wev_h = (bf16*)(ws + 200 * MBY), *Wev_l = (bf16*)(ws + 202 * MBY);
    bf16* Woa_h = (bf16*)(ws + 204 * MBY), *Woa_l = (bf16*)(ws + 206 * MBY);
    bf16* QH_h = (bf16*)(ws + 208 * MBY), *QH_l = (bf16*)(ws + 216 * MBY);
    bf16* KH_h = (bf16*)(ws + 224 * MBY), *KH_l = (bf16*)(ws + 232 * MBY);
    bf16* VH_h = (bf16*)(ws + 240 * MBY), *VH_l = (bf16*)(ws + 248 * MBY);
    bf16* VT_h = (bf16*)(ws + 256 * MBY), *VT_l = (bf16*)(ws + 264 * MBY);
    bf16* O_h  = (bf16*)(ws + 272 * MBY), *O_l  = (bf16*)(ws + 280 * MBY);
    float* Af  = (float*)(ws + 288 * MBY);   // 16MB
    float* Xf  = (float*)(ws + 304 * MBY);   // 16MB
    bf16* Xb   = (bf16*)(ws + 320 * MBY);    // 8MB
    float* combine  = (float*)(ws + 328 * MBY);              // 128KB
    float* partials = (float*)(ws + 328 * MBY + 256 * 1024); // 64KB
    float* beff     = (float*)(ws + 328 * MBY + 512 * 1024); // 3*4KB
    float* b_oa     = (float*)(ws + 328 * MBY + 528 * 1024); // 4KB

    dim3 blk(256);

    // ---- conversions ----
    k_f32_to_split<<<4096, blk, 0, stream>>>(query, Xq_h, Xq_l, 4L * MB1);
    k_f32_to_split<<<4096, blk, 0, stream>>>(key_value, Xkv_h, Xkv_l, 4L * MB1);
    k_f32_to_split<<<3072, blk, 0, stream>>>(W_in, Win_h, Win_l, 3L * MB1);
    k_f32_to_split<<<1024, blk, 0, stream>>>(Wa, Wa_h, Wa_l, MB1);
    k_transpose_f32_split<<<dim3(16, 16), blk, 0, stream>>>(Wq, WqT_h, WqT_l, 1024, 1024);
    k_transpose_f32_split<<<dim3(16, 16), blk, 0, stream>>>(Wk, WkT_h, WkT_l, 1024, 1024);
    k_transpose_f32_split<<<dim3(16, 16), blk, 0, stream>>>(Wv, WvT_h, WvT_l, 1024, 1024);
    k_transpose_f32_split<<<dim3(16, 16), blk, 0, stream>>>(W_out, WoT_h, WoT_l, 1024, 1024);
    k_transpose_to_bf16<float><<<dim3(64, 16, 8), blk, 0, stream>>>(ew1, ew1t, 1024, 4096, 4194304L, 4194304L);
    k_transpose_to_bf16<float><<<dim3(16, 64, 8), blk, 0, stream>>>(ew2, ew2t, 4096, 1024, 4194304L, 4194304L);
    // bias folds: beff_s = b_in_s + Wi_s @ b_s ; b_oa = ba + Wa @ b_out
    k_bias_fold<<<256, blk, 0, stream>>>(W_in,           bq, b_in,        beff);
    k_bias_fold<<<256, blk, 0, stream>>>(W_in + MB1,     bk, b_in + 1024, beff + 1024);
    k_bias_fold<<<256, blk, 0, stream>>>(W_in + 2 * MB1, bv, b_in + 2048, beff + 2048);
    k_bias_fold<<<256, blk, 0, stream>>>(Wa, b_out, ba, b_oa);

    // ---- weight folds: Weff_s = Wi_s @ W_s (B = W^T split); W_oa = Wa @ Wo ----
    dim3 gW(8, 8, 1);
    gemm_hp<HP_SPLIT><<<gW, blk, 0, stream>>>(Win_h, Win_l, 1024, 0, WqT_h, WqT_l, 1024, 0,
                                              Weq_h, Weq_l, 1024, 0, nullptr, 1.f, 1024, 1024, 1024);
    gemm_hp<HP_SPLIT><<<gW, blk, 0, stream>>>(Win_h + MB1, Win_l + MB1, 1024, 0, WkT_h, WkT_l, 1024, 0,
                                              Wek_h, Wek_l, 1024, 0, nullptr, 1.f, 1024, 1024, 1024);
    gemm_hp<HP_SPLIT><<<gW, blk, 0, stream>>>(Win_h + 2 * MB1, Win_l + 2 * MB1, 1024, 0, WvT_h, WvT_l, 1024, 0,
                                              Wev_h, Wev_l, 1024, 0, nullptr, 1.f, 1024, 1024, 1024);
    gemm_hp<HP_SPLIT><<<gW, blk, 0, stream>>>(Wa_h, Wa_l, 1024, 0, WoT_h, WoT_l, 1024, 0,
                                              Woa_h, Woa_l, 1024, 0, nullptr, 1.f, 1024, 1024, 1024);

    // ---- fused projections: QH/KH/VH ----
    dim3 gP(8, 32, 1);
    gemm_hp<HP_SPLIT><<<gP, blk, 0, stream>>>(Xq_h, Xq_l, 1024, 0, Weq_h, Weq_l, 1024, 0,
                                              QH_h, QH_l, 1024, 0, beff, 1.f, 4096, 1024, 1024);
    gemm_hp<HP_SPLIT><<<gP, blk, 0, stream>>>(Xkv_h, Xkv_l, 1024, 0, Wek_h, Wek_l, 1024, 0,
                                              KH_h, KH_l, 1024, 0, beff + 1024, 1.f, 4096, 1024, 1024);
    gemm_hp<HP_SPLIT><<<gP, blk, 0, stream>>>(Xkv_h, Xkv_l, 1024, 0, Wev_h, Wev_l, 1024, 0,
                                              VH_h, VH_l, 1024, 0, beff + 2048, 1.f, 4096, 1024, 1024);

    // V^T: [4096][1024] -> [1024][4096] (hi and lo separately — exact)
    k_transpose_to_bf16<bf16><<<dim3(16, 64, 1), blk, 0, stream>>>(VH_h, VT_h, 4096, 1024, 0L, 0L);
    k_transpose_to_bf16<bf16><<<dim3(16, 64, 1), blk, 0, stream>>>(VH_l, VT_l, 4096, 1024, 0L, 0L);

    // ---- attention: 8 chunks of (batch, 8 heads) ----
    for (int c = 0; c < 8; c++) {
        int b = c >> 1, h0 = (c & 1) * 8;
        long qoff = (long)b * MB1 + h0 * 64;
        gemm_hp<HP_F32><<<dim3(8, 8, 8), blk, 0, stream>>>(
            QH_h + qoff, QH_l + qoff, 1024, 64,
            KH_h + qoff, KH_l + qoff, 1024, 64,
            S, nullptr, 1024, MB1, nullptr, 0.125f, 1024, 1024, 64);
        k_softmax_split<<<2048, blk, 0, stream>>>(S, Ph, Pl);
        long voff = (long)(h0 * 64) * 4096 + (long)b * 1024;
        gemm_hp<HP_SPLIT><<<dim3(1, 8, 8), blk, 0, stream>>>(
            Ph, Pl, 1024, MB1,
            VT_h + voff, VT_l + voff, 4096, 64L * 4096,
            O_h + qoff, O_l + qoff, 1024, 64, nullptr, 1.f, 1024, 64, 1024);
    }

    // ---- fused out-proj+adapter: Af = O @ (Wa@Wo)^T + b_oa ----
    gemm_hp<HP_F32><<<gP, blk, 0, stream>>>(O_h, O_l, 1024, 0, Woa_h, Woa_l, 1024, 0,
                                            Af, nullptr, 1024, 0, b_oa, 1.f, 4096, 1024, 1024);
    k_ln<<<1024, blk, 0, stream>>>(Af, query, ln1_g, ln1_b, Xf, Xb);
    k_gate<<<1024, blk, 0, stream>>>(Xf, Wg, combine, partials);

    // ---- MoE dense with per-row combine scale ----
    hipMemsetAsync(moe_out, 0, (long)4096 * 1024 * 4, stream);
    for (int e = 0; e < 8; e++) {
        gemm_bt<EPI_GELU_BF16><<<dim3(32, 32), blk, 0, stream>>>(
            Xb, 1024, ew1t + (long)e * 4 * MB1, 1024, Hbuf, 4096,
            eb1 + (long)e * 4096, nullptr, 0, 4096, 4096, 1024);
        gemm_bt<EPI_ACC_ROWSCALE><<<dim3(8, 32), blk, 0, stream>>>(
            Hbuf, 4096, ew2t + (long)e * 4 * MB1, 4096, moe_out, 1024,
            eb2 + (long)e * 1024, combine + e, 8, 4096, 1024, 4096);
    }

    // ---- LN2 + aux ----
    k_ln<<<1024, blk, 0, stream>>>(moe_out, Xf, ln2_g, ln2_b, (float*)d_out, nullptr);
    k_aux<<<1, blk, 0, stream>>>(partials, 1024, (float*)d_out + (out_size - 1));
}

// Round 3
// 3276.126 us; speedup vs baseline: 1.0337x; 1.0337x over previous
//
#include <hip/hip_runtime.h>
#include <math.h>

#define THRESH_C 0.05f
#define COEF_C   0.01f

typedef __bf16 bf16;
typedef __bf16 bf16x8 __attribute__((ext_vector_type(8)));
typedef __bf16 bf16x4 __attribute__((ext_vector_type(4)));
typedef float  f32x4  __attribute__((ext_vector_type(4)));

// async global->LDS, 16B per lane, dest = wave-uniform base + lane*16
__device__ __forceinline__ void ld16(void* lds_base, const void* g) {
    __builtin_amdgcn_global_load_lds(
        (const __attribute__((address_space(1))) void*)g,
        (__attribute__((address_space(3))) void*)lds_base,
        16, 0, 0);
}

// ---------------- f32 -> split (hi+lo bf16) ----------------
__global__ __launch_bounds__(256) void k_f32_to_split(const float* __restrict__ in,
                                                      bf16* __restrict__ hi,
                                                      bf16* __restrict__ lo, long n) {
    long i = ((long)blockIdx.x * 256 + threadIdx.x) * 4;
    if (i >= n) return;
    float4 v = *(const float4*)(in + i);
    bf16x4 h, l;
    h[0] = (bf16)v.x; l[0] = (bf16)(v.x - (float)h[0]);
    h[1] = (bf16)v.y; l[1] = (bf16)(v.y - (float)h[1]);
    h[2] = (bf16)v.z; l[2] = (bf16)(v.z - (float)h[2]);
    h[3] = (bf16)v.w; l[3] = (bf16)(v.w - (float)h[3]);
    *(bf16x4*)(hi + i) = h;
    *(bf16x4*)(lo + i) = l;
}

// ---------------- f32 transpose -> split ----------------
__global__ __launch_bounds__(256) void k_transpose_f32_split(const float* __restrict__ in,
                                                             bf16* __restrict__ oh,
                                                             bf16* __restrict__ ol,
                                                             int R, int C) {
    __shared__ float t[64][65];
    int r0 = blockIdx.y * 64, c0 = blockIdx.x * 64;
    for (int i = threadIdx.x; i < 4096; i += 256) {
        int r = i >> 6, c = i & 63;
        t[r][c] = in[(long)(r0 + r) * C + (c0 + c)];
    }
    __syncthreads();
    for (int i = threadIdx.x; i < 4096; i += 256) {
        int c = i >> 6, r = i & 63;
        float v = t[r][c];
        bf16 h = (bf16)v;
        long o = (long)(c0 + c) * R + (r0 + r);
        oh[o] = h;
        ol[o] = (bf16)(v - (float)h);
    }
}

// ---------------- generic transpose to bf16 (single) ----------------
template<typename Tin>
__global__ __launch_bounds__(256) void k_transpose_to_bf16(const Tin* __restrict__ in,
                                                           bf16* __restrict__ out,
                                                           int R, int C,
                                                           long inStride, long outStride) {
    __shared__ bf16 t[64][65];
    const Tin* ib = in + (long)blockIdx.z * inStride;
    bf16* ob = out + (long)blockIdx.z * outStride;
    int r0 = blockIdx.y * 64, c0 = blockIdx.x * 64;
    for (int i = threadIdx.x; i < 4096; i += 256) {
        int r = i >> 6, c = i & 63;
        t[r][c] = (bf16)(float)ib[(long)(r0 + r) * C + (c0 + c)];
    }
    __syncthreads();
    for (int i = threadIdx.x; i < 4096; i += 256) {
        int c = i >> 6, r = i & 63;
        ob[(long)(c0 + c) * R + (r0 + r)] = t[r][c];
    }
}

// ---------------- bias fold: y = b2 + W @ b1 ----------------
__global__ __launch_bounds__(256) void k_bias_fold(const float* __restrict__ W,
                                                   const float* __restrict__ b1,
                                                   const float* __restrict__ b2,
                                                   float* __restrict__ y) {
    int row = blockIdx.x * 4 + (threadIdx.x >> 6);
    int lane = threadIdx.x & 63;
    const float* wr = W + (long)row * 1024;
    float s = 0.f;
    for (int k = lane; k < 1024; k += 64) s += wr[k] * b1[k];
#pragma unroll
    for (int o = 32; o >= 1; o >>= 1) s += __shfl_xor(s, o);
    if (lane == 0) y[row] = b2[row] + s;
}

// ---------------- high-precision split-bf16 GEMM: C = alpha*(A @ B^T) + bias ----------------
enum { HP_SPLIT = 0, HP_F32 = 1 };

template<int MODE>
__global__ __launch_bounds__(256)
void gemm_hp(const bf16* __restrict__ Ah, const bf16* __restrict__ Al, int lda, long sAz,
             const bf16* __restrict__ Bh, const bf16* __restrict__ Bl, int ldb, long sBz,
             void* __restrict__ Chv, bf16* __restrict__ Cl, int ldc, long sCz,
             const float* __restrict__ bias, float alpha, int M, int N, int K) {
    __shared__ alignas(16) bf16 sAh[128 * 32];
    __shared__ alignas(16) bf16 sAl[128 * 32];
    __shared__ alignas(16) bf16 sBh[128 * 32];
    __shared__ alignas(16) bf16 sBl[128 * 32];
    const int bm = blockIdx.y, bn = blockIdx.x, z = blockIdx.z;
    const int tid  = threadIdx.x;
    const int lane = tid & 63, wave = tid >> 6;
    const int quad = lane >> 4, l16 = lane & 15;
    const int wr = wave >> 1, wc = wave & 1;
    const int sr = tid >> 2;
    const int sc = (tid & 3) * 8;

    int arow0 = min(bm * 128 + sr, M - 1);
    int arow1 = min(bm * 128 + sr + 64, M - 1);
    int brow0 = min(bn * 128 + sr, N - 1);
    int brow1 = min(bn * 128 + sr + 64, N - 1);

    const bf16* pAh0 = Ah + (long)z * sAz + (long)arow0 * lda + sc;
    const bf16* pAh1 = Ah + (long)z * sAz + (long)arow1 * lda + sc;
    const bf16* pAl0 = Al + (long)z * sAz + (long)arow0 * lda + sc;
    const bf16* pAl1 = Al + (long)z * sAz + (long)arow1 * lda + sc;
    const bf16* pBh0 = Bh + (long)z * sBz + (long)brow0 * ldb + sc;
    const bf16* pBh1 = Bh + (long)z * sBz + (long)brow1 * ldb + sc;
    const bf16* pBl0 = Bl + (long)z * sBz + (long)brow0 * ldb + sc;
    const bf16* pBl1 = Bl + (long)z * sBz + (long)brow1 * ldb + sc;
    const int wo = wave << 9;   // wave LDS element offset (512 bf16 = 1KB)

    f32x4 acc[4][4];
#pragma unroll
    for (int i = 0; i < 4; i++)
#pragma unroll
        for (int j = 0; j < 4; j++) acc[i][j] = (f32x4){0.f, 0.f, 0.f, 0.f};

    for (int k0 = 0; k0 < K; k0 += 32) {
        __syncthreads();
        ld16(sAh + wo,        pAh0 + k0);
        ld16(sAh + 2048 + wo, pAh1 + k0);
        ld16(sAl + wo,        pAl0 + k0);
        ld16(sAl + 2048 + wo, pAl1 + k0);
        ld16(sBh + wo,        pBh0 + k0);
        ld16(sBh + 2048 + wo, pBh1 + k0);
        ld16(sBl + wo,        pBl0 + k0);
        ld16(sBl + 2048 + wo, pBl1 + k0);
        __syncthreads();
        bf16x8 ah[4], al[4], bh[4], bl[4];
#pragma unroll
        for (int i = 0; i < 4; i++) {
            int ro = (wr * 64 + i * 16 + l16) * 32 + quad * 8;
            ah[i] = *(const bf16x8*)&sAh[ro];
            al[i] = *(const bf16x8*)&sAl[ro];
        }
#pragma unroll
        for (int j = 0; j < 4; j++) {
            int ro = (wc * 64 + j * 16 + l16) * 32 + quad * 8;
            bh[j] = *(const bf16x8*)&sBh[ro];
            bl[j] = *(const bf16x8*)&sBl[ro];
        }
#pragma unroll
        for (int i = 0; i < 4; i++)
#pragma unroll
            for (int j = 0; j < 4; j++) {
                acc[i][j] = __builtin_amdgcn_mfma_f32_16x16x32_bf16(al[i], bh[j], acc[i][j], 0, 0, 0);
                acc[i][j] = __builtin_amdgcn_mfma_f32_16x16x32_bf16(ah[i], bl[j], acc[i][j], 0, 0, 0);
                acc[i][j] = __builtin_amdgcn_mfma_f32_16x16x32_bf16(ah[i], bh[j], acc[i][j], 0, 0, 0);
            }
    }

#pragma unroll
    for (int i = 0; i < 4; i++) {
        int mbase = bm * 128 + wr * 64 + i * 16 + quad * 4;
#pragma unroll
        for (int j = 0; j < 4; j++) {
            int n = bn * 128 + wc * 64 + j * 16 + l16;
            if (n < N) {
                float bv = bias ? bias[n] : 0.f;
#pragma unroll
                for (int r = 0; r < 4; r++) {
                    int m = mbase + r;
                    if (m < M) {
                        float v = alpha * acc[i][j][r] + bv;
                        long cidx = (long)z * sCz + (long)m * ldc + n;
                        if (MODE == HP_SPLIT) {
                            bf16 h = (bf16)v;
                            ((bf16*)Chv)[cidx] = h;
                            Cl[cidx] = (bf16)(v - (float)h);
                        } else {
                            ((float*)Chv)[cidx] = v;
                        }
                    }
                }
            }
        }
    }
}

// ---------------- routed MoE GEMMs (dynamic M from device counter) ----------------
enum { MOE_GELU = 0, MOE_SCATTER = 1 };

template<int MODE>
__global__ __launch_bounds__(256)
void gemm_moe(const bf16* __restrict__ A, int lda,
              const bf16* __restrict__ B, int ldb,
              void* __restrict__ Cv, int ldc,
              const float* __restrict__ bias,
              const int* __restrict__ cntp,
              const int* __restrict__ tok,
              const float* __restrict__ combine, int eidx,
              int N, int K) {
    __shared__ alignas(16) bf16 sA[128 * 32];
    __shared__ alignas(16) bf16 sB[128 * 32];
    const int bm = blockIdx.y, bn = blockIdx.x;
    const int M = *cntp;
    if (bm * 128 >= M) return;
    const int tid  = threadIdx.x;
    const int lane = tid & 63, wave = tid >> 6;
    const int quad = lane >> 4, l16 = lane & 15;
    const int wr = wave >> 1, wc = wave & 1;
    const int sr = tid >> 2;
    const int sc = (tid & 3) * 8;

    int arow0 = min(bm * 128 + sr, M - 1);
    int arow1 = min(bm * 128 + sr + 64, M - 1);
    int brow0 = bn * 128 + sr;
    int brow1 = brow0 + 64;
    const bf16* pA0 = A + (long)arow0 * lda + sc;
    const bf16* pA1 = A + (long)arow1 * lda + sc;
    const bf16* pB0 = B + (long)brow0 * ldb + sc;
    const bf16* pB1 = B + (long)brow1 * ldb + sc;
    const int wo = wave << 9;

    f32x4 acc[4][4];
#pragma unroll
    for (int i = 0; i < 4; i++)
#pragma unroll
        for (int j = 0; j < 4; j++) acc[i][j] = (f32x4){0.f, 0.f, 0.f, 0.f};

    for (int k0 = 0; k0 < K; k0 += 32) {
        __syncthreads();
        ld16(sA + wo,        pA0 + k0);
        ld16(sA + 2048 + wo, pA1 + k0);
        ld16(sB + wo,        pB0 + k0);
        ld16(sB + 2048 + wo, pB1 + k0);
        __syncthreads();
        bf16x8 af[4], bfr[4];
#pragma unroll
        for (int i = 0; i < 4; i++)
            af[i] = *(const bf16x8*)&sA[(wr * 64 + i * 16 + l16) * 32 + quad * 8];
#pragma unroll
        for (int j = 0; j < 4; j++)
            bfr[j] = *(const bf16x8*)&sB[(wc * 64 + j * 16 + l16) * 32 + quad * 8];
#pragma unroll
        for (int i = 0; i < 4; i++)
#pragma unroll
            for (int j = 0; j < 4; j++)
                acc[i][j] = __builtin_amdgcn_mfma_f32_16x16x32_bf16(af[i], bfr[j], acc[i][j], 0, 0, 0);
    }

#pragma unroll
    for (int i = 0; i < 4; i++) {
        int mbase = bm * 128 + wr * 64 + i * 16 + quad * 4;
#pragma unroll
        for (int j = 0; j < 4; j++) {
            int n = bn * 128 + wc * 64 + j * 16 + l16;
            float bv = bias[n];
#pragma unroll
            for (int r = 0; r < 4; r++) {
                int m = mbase + r;
                if (m < M) {
                    float v = acc[i][j][r] + bv;
                    if (MODE == MOE_GELU) {
                        float g = 0.5f * v * (1.f + erff(v * 0.70710678118654752f));
                        ((bf16*)Cv)[(long)m * ldc + n] = (bf16)g;
                    } else {
                        int t = tok[m];
                        float s = combine[t * 8 + eidx];
                        if (s != 0.f) ((float*)Cv)[(long)t * ldc + n] += s * v;
                    }
                }
            }
        }
    }
}

// ---------------- gather expert rows ----------------
__global__ __launch_bounds__(256) void k_gather(const bf16* __restrict__ Xb,
                                                const int* __restrict__ tok,
                                                const int* __restrict__ counts,
                                                bf16* __restrict__ Ae) {
    int e = blockIdx.y, i = blockIdx.x;
    if (i >= counts[e]) return;
    int t = tok[e * 4096 + i];
    const bf16x4* src = (const bf16x4*)(Xb + (long)t * 1024);
    bf16x4* dst = (bf16x4*)(Ae + ((long)e * 4096 + i) * 1024);
    dst[threadIdx.x] = src[threadIdx.x];
}

// ---------------- softmax rows (f32 in, split bf16 out) ----------------
__global__ __launch_bounds__(256) void k_softmax_split(const float* __restrict__ S,
                                                       bf16* __restrict__ Ph,
                                                       bf16* __restrict__ Pl) {
    int row = blockIdx.x * 4 + (threadIdx.x >> 6);
    int lane = threadIdx.x & 63;
    const float* p = S + (long)row * 1024 + lane * 16;
    float v[16];
#pragma unroll
    for (int i = 0; i < 16; i += 4) {
        f32x4 a = *(const f32x4*)(p + i);
        v[i] = a[0]; v[i + 1] = a[1]; v[i + 2] = a[2]; v[i + 3] = a[3];
    }
    float mx = v[0];
#pragma unroll
    for (int i = 1; i < 16; i++) mx = fmaxf(mx, v[i]);
#pragma unroll
    for (int o = 32; o >= 1; o >>= 1) mx = fmaxf(mx, __shfl_xor(mx, o));
    float s = 0.f;
#pragma unroll
    for (int i = 0; i < 16; i++) { v[i] = expf(v[i] - mx); s += v[i]; }
#pragma unroll
    for (int o = 32; o >= 1; o >>= 1) s += __shfl_xor(s, o);
    float inv = 1.f / s;
    bf16x8 h0, h1, l0, l1;
#pragma unroll
    for (int i = 0; i < 8; i++) {
        float a = v[i] * inv;
        h0[i] = (bf16)a; l0[i] = (bf16)(a - (float)h0[i]);
        float b = v[8 + i] * inv;
        h1[i] = (bf16)b; l1[i] = (bf16)(b - (float)h1[i]);
    }
    long o = (long)row * 1024 + lane * 16;
    *(bf16x8*)(Ph + o) = h0;  *(bf16x8*)(Ph + o + 8) = h1;
    *(bf16x8*)(Pl + o) = l0;  *(bf16x8*)(Pl + o + 8) = l1;
}

// ---------------- layernorm ----------------
__global__ __launch_bounds__(256) void k_ln(const float* __restrict__ xin,
                                            const float* __restrict__ resid,
                                            const float* __restrict__ g,
                                            const float* __restrict__ bb,
                                            float* __restrict__ outf,
                                            bf16* __restrict__ outb) {
    int row = blockIdx.x * 4 + (threadIdx.x >> 6);
    int lane = threadIdx.x & 63;
    long base = (long)row * 1024 + lane * 16;
    float v[16];
#pragma unroll
    for (int i = 0; i < 16; i += 4) {
        f32x4 a = *(const f32x4*)(xin + base + i);
        if (resid) { f32x4 r4 = *(const f32x4*)(resid + base + i); a += r4; }
        v[i] = a[0]; v[i + 1] = a[1]; v[i + 2] = a[2]; v[i + 3] = a[3];
    }
    float s = 0.f;
#pragma unroll
    for (int i = 0; i < 16; i++) s += v[i];
#pragma unroll
    for (int o = 32; o >= 1; o >>= 1) s += __shfl_xor(s, o);
    float mean = s * (1.f / 1024.f);
    float vs = 0.f;
#pragma unroll
    for (int i = 0; i < 16; i++) { float d = v[i] - mean; vs += d * d; }
#pragma unroll
    for (int o = 32; o >= 1; o >>= 1) vs += __shfl_xor(vs, o);
    float inv = 1.f / sqrtf(vs * (1.f / 1024.f) + 1e-5f);
    const float* gp = g + lane * 16;
    const float* bp = bb + lane * 16;
#pragma unroll
    for (int i = 0; i < 16; i++) {
        float o = (v[i] - mean) * inv * gp[i] + bp[i];
        if (outf) outf[base + i] = o;
        if (outb) outb[base + i] = (bf16)o;
    }
}

// ---------------- MoE gating + routing ----------------
__global__ __launch_bounds__(256) void k_gate(const float* __restrict__ X,
                                              const float* __restrict__ Wg,
                                              float* __restrict__ combine,
                                              float* __restrict__ partials,
                                              int* __restrict__ counts,
                                              int* __restrict__ tok) {
    __shared__ float sm[16];
    if (threadIdx.x < 16) sm[threadIdx.x] = 0.f;
    __syncthreads();
    int t = blockIdx.x * 4 + (threadIdx.x >> 6);
    int lane = threadIdx.x & 63;
    const float* x = X + (long)t * 1024;
    float acc[8] = {0.f, 0.f, 0.f, 0.f, 0.f, 0.f, 0.f, 0.f};
    for (int i = lane; i < 1024; i += 64) {
        float xv = x[i];
        const float* w = Wg + i * 8;
#pragma unroll
        for (int e = 0; e < 8; e++) acc[e] += xv * w[e];
    }
#pragma unroll
    for (int e = 0; e < 8; e++)
#pragma unroll
        for (int o = 32; o >= 1; o >>= 1) acc[e] += __shfl_xor(acc[e], o);
    if (lane == 0) {
        float mx = acc[0];
#pragma unroll
        for (int e = 1; e < 8; e++) mx = fmaxf(mx, acc[e]);
        float p[8], s = 0.f;
#pragma unroll
        for (int e = 0; e < 8; e++) { p[e] = expf(acc[e] - mx); s += p[e]; }
        float invs = 1.f / s;
#pragma unroll
        for (int e = 0; e < 8; e++) p[e] *= invs;
        float b1 = -1.f, b2 = -1.f, b3 = -1.f; int i1 = 0, i2 = 0, i3 = 0;
#pragma unroll
        for (int e = 0; e < 8; e++) {
            float pe = p[e];
            if (pe > b1)      { b3 = b2; i3 = i2; b2 = b1; i2 = i1; b1 = pe; i1 = e; }
            else if (pe > b2) { b3 = b2; i3 = i2; b2 = pe; i2 = e; }
            else if (pe > b3) { b3 = pe; i3 = e; }
        }
        float c[8] = {0.f, 0.f, 0.f, 0.f, 0.f, 0.f, 0.f, 0.f};
        c[i1] = b1;
        if (b2 >= THRESH_C) c[i2] = b2;
        if (b3 >= THRESH_C) c[i3] = b3;
        float* co = combine + (long)t * 8;
#pragma unroll
        for (int e = 0; e < 8; e++) co[e] = c[e];
#pragma unroll
        for (int e = 0; e < 8; e++) {
            atomicAdd(&sm[e], p[e]);
            if (c[e] > 0.f) {
                atomicAdd(&sm[8 + e], 1.f);
                int slot = atomicAdd(&counts[e], 1);
                tok[e * 4096 + slot] = t;
            }
        }
    }
    __syncthreads();
    if (threadIdx.x < 16) partials[(long)blockIdx.x * 16 + threadIdx.x] = sm[threadIdx.x];
}

// ---------------- aux reduce ----------------
__global__ __launch_bounds__(256) void k_aux(const float* __restrict__ partials, int nblocks,
                                             float* __restrict__ auxout) {
    __shared__ float red[256];
    int tid = threadIdx.x;
    int e = tid & 15, grp = tid >> 4;
    float s = 0.f;
    for (int b = grp; b < nblocks; b += 16) s += partials[(long)b * 16 + e];
    red[tid] = s;
    __syncthreads();
    if (grp == 0) {
        float tot = 0.f;
        for (int g2 = 0; g2 < 16; g2++) tot += red[g2 * 16 + e];
        red[tid] = tot;
    }
    __syncthreads();
    if (tid == 0) {
        float s2 = 0.f;
        for (int e2 = 0; e2 < 8; e2++)
            s2 += (red[8 + e2] * (1.f / 4096.f)) * (red[e2] * (1.f / 4096.f));
        auxout[0] = COEF_C * 8.f * s2;
    }
}

// ---------------- host ----------------
extern "C" void kernel_launch(void* const* d_in, const int* in_sizes, int n_in,
                              void* d_out, int out_size, void* d_ws, size_t ws_size,
                              hipStream_t stream) {
    const float* query     = (const float*)d_in[0];
    const float* key_value = (const float*)d_in[1];
    const float* Wq   = (const float*)d_in[2];
    const float* bq   = (const float*)d_in[3];
    const float* Wk   = (const float*)d_in[4];
    const float* bk   = (const float*)d_in[5];
    const float* Wv   = (const float*)d_in[6];
    const float* bv   = (const float*)d_in[7];
    const float* W_in = (const float*)d_in[8];
    const float* b_in = (const float*)d_in[9];
    const float* W_out = (const float*)d_in[10];
    const float* b_out = (const float*)d_in[11];
    const float* Wa   = (const float*)d_in[12];
    const float* ba   = (const float*)d_in[13];
    const float* ln1_g = (const float*)d_in[14];
    const float* ln1_b = (const float*)d_in[15];
    const float* Wg   = (const float*)d_in[16];
    const float* ew1  = (const float*)d_in[17];
    const float* eb1  = (const float*)d_in[18];
    const float* ew2  = (const float*)d_in[19];
    const float* eb2  = (const float*)d_in[20];
    const float* ln2_g = (const float*)d_in[21];
    const float* ln2_b = (const float*)d_in[22];

    const size_t MBY = 1ull << 20;
    const long MB1 = 1024L * 1024L;
    char* ws = (char*)d_ws;

    bf16* ew1t = (bf16*)(ws + 0 * MBY);      // 64MB
    bf16* ew2t = (bf16*)(ws + 64 * MBY);     // 64MB
    char* R1   = ws + 128 * MBY;             // 64MB multi-phase region
    // phase A (prep)
    bf16* WqT_h = (bf16*)(R1 + 0 * MBY),  *WqT_l = (bf16*)(R1 + 2 * MBY);
    bf16* WkT_h = (bf16*)(R1 + 4 * MBY),  *WkT_l = (bf16*)(R1 + 6 * MBY);
    bf16* WvT_h = (bf16*)(R1 + 8 * MBY),  *WvT_l = (bf16*)(R1 + 10 * MBY);
    bf16* WoT_h = (bf16*)(R1 + 12 * MBY), *WoT_l = (bf16*)(R1 + 14 * MBY);
    bf16* Win_h = (bf16*)(R1 + 16 * MBY), *Win_l = (bf16*)(R1 + 22 * MBY);
    bf16* Wa_h  = (bf16*)(R1 + 28 * MBY), *Wa_l  = (bf16*)(R1 + 30 * MBY);
    bf16* Xq_h  = (bf16*)(R1 + 32 * MBY), *Xq_l  = (bf16*)(R1 + 40 * MBY);
    bf16* Xkv_h = (bf16*)(R1 + 48 * MBY), *Xkv_l = (bf16*)(R1 + 56 * MBY);
    // phase B (attention)
    float* S  = (float*)(R1 + 0 * MBY);      // 32MB
    bf16* Ph  = (bf16*)(R1 + 32 * MBY);      // 16MB
    bf16* Pl  = (bf16*)(R1 + 48 * MBY);      // 16MB
    // phase C (MoE)
    bf16* Hbuf     = (bf16*)(R1 + 0 * MBY);  // 32MB
    float* moe_out = (float*)(R1 + 32 * MBY);// 16MB
    // persistent (attention phase); [192,256) reused as Ae in MoE phase
    bf16* Weq_h = (bf16*)(ws + 192 * MBY), *Weq_l = (bf16*)(ws + 194 * MBY);
    bf16* Wek_h = (bf16*)(ws + 196 * MBY), *Wek_l = (bf16*)(ws + 198 * MBY);
    bf16* Wev_h = (bf16*)(ws + 200 * MBY), *Wev_l = (bf16*)(ws + 202 * MBY);
    bf16* Woa_h = (bf16*)(ws + 204 * MBY), *Woa_l = (bf16*)(ws + 206 * MBY);
    bf16* QH_h = (bf16*)(ws + 208 * MBY), *QH_l = (bf16*)(ws + 216 * MBY);
    bf16* KH_h = (bf16*)(ws + 224 * MBY), *KH_l = (bf16*)(ws + 232 * MBY);
    bf16* VH_h = (bf16*)(ws + 240 * MBY), *VH_l = (bf16*)(ws + 248 * MBY);
    bf16* VT_h = (bf16*)(ws + 256 * MBY), *VT_l = (bf16*)(ws + 264 * MBY);
    bf16* O_h  = (bf16*)(ws + 272 * MBY), *O_l  = (bf16*)(ws + 280 * MBY);
    bf16* Ae   = (bf16*)(ws + 192 * MBY);    // 64MB, MoE phase (aliases dead weights/QH/KH/VH)
    float* Af  = (float*)(ws + 288 * MBY);
    float* Xf  = (float*)(ws + 304 * MBY);
    bf16* Xb   = (bf16*)(ws + 320 * MBY);
    float* combine  = (float*)(ws + 328 * MBY);               // 128KB
    float* partials = (float*)(ws + 328 * MBY + 256 * 1024);  // 64KB
    float* beff     = (float*)(ws + 328 * MBY + 384 * 1024);  // 12KB
    float* b_oa     = (float*)(ws + 328 * MBY + 400 * 1024);  // 4KB
    int*   counts   = (int*)  (ws + 328 * MBY + 416 * 1024);  // 32B
    int*   tok      = (int*)  (ws + 328 * MBY + 512 * 1024);  // 128KB

    dim3 blk(256);

    // ---- conversions ----
    k_f32_to_split<<<4096, blk, 0, stream>>>(query, Xq_h, Xq_l, 4L * MB1);
    k_f32_to_split<<<4096, blk, 0, stream>>>(key_value, Xkv_h, Xkv_l, 4L * MB1);
    k_f32_to_split<<<3072, blk, 0, stream>>>(W_in, Win_h, Win_l, 3L * MB1);
    k_f32_to_split<<<1024, blk, 0, stream>>>(Wa, Wa_h, Wa_l, MB1);
    k_transpose_f32_split<<<dim3(16, 16), blk, 0, stream>>>(Wq, WqT_h, WqT_l, 1024, 1024);
    k_transpose_f32_split<<<dim3(16, 16), blk, 0, stream>>>(Wk, WkT_h, WkT_l, 1024, 1024);
    k_transpose_f32_split<<<dim3(16, 16), blk, 0, stream>>>(Wv, WvT_h, WvT_l, 1024, 1024);
    k_transpose_f32_split<<<dim3(16, 16), blk, 0, stream>>>(W_out, WoT_h, WoT_l, 1024, 1024);
    k_transpose_to_bf16<float><<<dim3(64, 16, 8), blk, 0, stream>>>(ew1, ew1t, 1024, 4096, 4194304L, 4194304L);
    k_transpose_to_bf16<float><<<dim3(16, 64, 8), blk, 0, stream>>>(ew2, ew2t, 4096, 1024, 4194304L, 4194304L);
    k_bias_fold<<<256, blk, 0, stream>>>(W_in,           bq, b_in,        beff);
    k_bias_fold<<<256, blk, 0, stream>>>(W_in + MB1,     bk, b_in + 1024, beff + 1024);
    k_bias_fold<<<256, blk, 0, stream>>>(W_in + 2 * MB1, bv, b_in + 2048, beff + 2048);
    k_bias_fold<<<256, blk, 0, stream>>>(Wa, b_out, ba, b_oa);

    // ---- weight folds ----
    dim3 gW(8, 8, 1);
    gemm_hp<HP_SPLIT><<<gW, blk, 0, stream>>>(Win_h, Win_l, 1024, 0, WqT_h, WqT_l, 1024, 0,
                                              Weq_h, Weq_l, 1024, 0, nullptr, 1.f, 1024, 1024, 1024);
    gemm_hp<HP_SPLIT><<<gW, blk, 0, stream>>>(Win_h + MB1, Win_l + MB1, 1024, 0, WkT_h, WkT_l, 1024, 0,
                                              Wek_h, Wek_l, 1024, 0, nullptr, 1.f, 1024, 1024, 1024);
    gemm_hp<HP_SPLIT><<<gW, blk, 0, stream>>>(Win_h + 2 * MB1, Win_l + 2 * MB1, 1024, 0, WvT_h, WvT_l, 1024, 0,
                                              Wev_h, Wev_l, 1024, 0, nullptr, 1.f, 1024, 1024, 1024);
    gemm_hp<HP_SPLIT><<<gW, blk, 0, stream>>>(Wa_h, Wa_l, 1024, 0, WoT_h, WoT_l, 1024, 0,
                                              Woa_h, Woa_l, 1024, 0, nullptr, 1.f, 1024, 1024, 1024);

    // ---- fused projections ----
    dim3 gP(8, 32, 1);
    gemm_hp<HP_SPLIT><<<gP, blk, 0, stream>>>(Xq_h, Xq_l, 1024, 0, Weq_h, Weq_l, 1024, 0,
                                              QH_h, QH_l, 1024, 0, beff, 1.f, 4096, 1024, 1024);
    gemm_hp<HP_SPLIT><<<gP, blk, 0, stream>>>(Xkv_h, Xkv_l, 1024, 0, Wek_h, Wek_l, 1024, 0,
                                              KH_h, KH_l, 1024, 0, beff + 1024, 1.f, 4096, 1024, 1024);
    gemm_hp<HP_SPLIT><<<gP, blk, 0, stream>>>(Xkv_h, Xkv_l, 1024, 0, Wev_h, Wev_l, 1024, 0,
                                              VH_h, VH_l, 1024, 0, beff + 2048, 1.f, 4096, 1024, 1024);

    k_transpose_to_bf16<bf16><<<dim3(16, 64, 1), blk, 0, stream>>>(VH_h, VT_h, 4096, 1024, 0L, 0L);
    k_transpose_to_bf16<bf16><<<dim3(16, 64, 1), blk, 0, stream>>>(VH_l, VT_l, 4096, 1024, 0L, 0L);

    // ---- attention: 8 chunks of (batch, 8 heads) ----
    for (int c = 0; c < 8; c++) {
        int b = c >> 1, h0 = (c & 1) * 8;
        long qoff = (long)b * MB1 + h0 * 64;
        gemm_hp<HP_F32><<<dim3(8, 8, 8), blk, 0, stream>>>(
            QH_h + qoff, QH_l + qoff, 1024, 64,
            KH_h + qoff, KH_l + qoff, 1024, 64,
            S, nullptr, 1024, MB1, nullptr, 0.125f, 1024, 1024, 64);
        k_softmax_split<<<2048, blk, 0, stream>>>(S, Ph, Pl);
        long voff = (long)(h0 * 64) * 4096 + (long)b * 1024;
        gemm_hp<HP_SPLIT><<<dim3(1, 8, 8), blk, 0, stream>>>(
            Ph, Pl, 1024, MB1,
            VT_h + voff, VT_l + voff, 4096, 64L * 4096,
            O_h + qoff, O_l + qoff, 1024, 64, nullptr, 1.f, 1024, 64, 1024);
    }

    // ---- fused out-proj+adapter + LN1 + gate ----
    gemm_hp<HP_F32><<<gP, blk, 0, stream>>>(O_h, O_l, 1024, 0, Woa_h, Woa_l, 1024, 0,
                                            Af, nullptr, 1024, 0, b_oa, 1.f, 4096, 1024, 1024);
    k_ln<<<1024, blk, 0, stream>>>(Af, query, ln1_g, ln1_b, Xf, Xb);
    hipMemsetAsync(counts, 0, 8 * sizeof(int), stream);
    k_gate<<<1024, blk, 0, stream>>>(Xf, Wg, combine, partials, counts, tok);

    // ---- routed MoE ----
    hipMemsetAsync(moe_out, 0, (long)4096 * 1024 * 4, stream);
    k_gather<<<dim3(4096, 8), blk, 0, stream>>>(Xb, tok, counts, Ae);
    for (int e = 0; e < 8; e++) {
        gemm_moe<MOE_GELU><<<dim3(32, 32), blk, 0, stream>>>(
            Ae + (long)e * 4 * MB1, 1024, ew1t + (long)e * 4 * MB1, 1024,
            Hbuf, 4096, eb1 + (long)e * 4096, counts + e, nullptr, nullptr, e, 4096, 1024);
        gemm_moe<MOE_SCATTER><<<dim3(8, 32), blk, 0, stream>>>(
            Hbuf, 4096, ew2t + (long)e * 4 * MB1, 4096,
            moe_out, 1024, eb2 + (long)e * 1024, counts + e, tok + e * 4096, combine, e, 1024, 4096);
    }

    // ---- LN2 + aux ----
    k_ln<<<1024, blk, 0, stream>>>(moe_out, Xf, ln2_g, ln2_b, (float*)d_out, nullptr);
    k_aux<<<1, blk, 0, stream>>>(partials, 1024, (float*)d_out + (out_size - 1));
}

// Round 4
// 1956.142 us; speedup vs baseline: 1.7312x; 1.6748x over previous
//
#include <hip/hip_runtime.h>
#include <math.h>

#define THRESH_C 0.05f
#define COEF_C   0.01f

typedef __bf16 bf16;
typedef __bf16 bf16x8 __attribute__((ext_vector_type(8)));
typedef __bf16 bf16x4 __attribute__((ext_vector_type(4)));
typedef float  f32x4  __attribute__((ext_vector_type(4)));

// async global->LDS, 16B per lane, dest = wave-uniform base + lane*16
__device__ __forceinline__ void ld16(void* lds_base, const void* g) {
    __builtin_amdgcn_global_load_lds(
        (const __attribute__((address_space(1))) void*)g,
        (__attribute__((address_space(3))) void*)lds_base,
        16, 0, 0);
}

// ---------------- f32 -> split (hi+lo bf16) ----------------
__global__ __launch_bounds__(256) void k_f32_to_split(const float* __restrict__ in,
                                                      bf16* __restrict__ hi,
                                                      bf16* __restrict__ lo, long n) {
    long i = ((long)blockIdx.x * 256 + threadIdx.x) * 4;
    if (i >= n) return;
    float4 v = *(const float4*)(in + i);
    bf16x4 h, l;
    h[0] = (bf16)v.x; l[0] = (bf16)(v.x - (float)h[0]);
    h[1] = (bf16)v.y; l[1] = (bf16)(v.y - (float)h[1]);
    h[2] = (bf16)v.z; l[2] = (bf16)(v.z - (float)h[2]);
    h[3] = (bf16)v.w; l[3] = (bf16)(v.w - (float)h[3]);
    *(bf16x4*)(hi + i) = h;
    *(bf16x4*)(lo + i) = l;
}

// ---------------- f32 transpose -> split ----------------
__global__ __launch_bounds__(256) void k_transpose_f32_split(const float* __restrict__ in,
                                                             bf16* __restrict__ oh,
                                                             bf16* __restrict__ ol,
                                                             int R, int C) {
    __shared__ float t[64][65];
    int r0 = blockIdx.y * 64, c0 = blockIdx.x * 64;
    for (int i = threadIdx.x; i < 4096; i += 256) {
        int r = i >> 6, c = i & 63;
        t[r][c] = in[(long)(r0 + r) * C + (c0 + c)];
    }
    __syncthreads();
    for (int i = threadIdx.x; i < 4096; i += 256) {
        int c = i >> 6, r = i & 63;
        float v = t[r][c];
        bf16 h = (bf16)v;
        long o = (long)(c0 + c) * R + (r0 + r);
        oh[o] = h;
        ol[o] = (bf16)(v - (float)h);
    }
}

// ---------------- generic transpose to bf16 ----------------
__global__ __launch_bounds__(256) void k_transpose_ew(const float* __restrict__ in,
                                                      bf16* __restrict__ out,
                                                      int R, int C) {
    __shared__ bf16 t[64][65];
    const float* ib = in + (long)blockIdx.z * R * C;
    bf16* ob = out + (long)blockIdx.z * R * C;
    int r0 = blockIdx.y * 64, c0 = blockIdx.x * 64;
    for (int i = threadIdx.x; i < 4096; i += 256) {
        int r = i >> 6, c = i & 63;
        t[r][c] = (bf16)ib[(long)(r0 + r) * C + (c0 + c)];
    }
    __syncthreads();
    for (int i = threadIdx.x; i < 4096; i += 256) {
        int c = i >> 6, r = i & 63;
        ob[(long)(c0 + c) * R + (r0 + r)] = t[r][c];
    }
}

// ---------------- bias fold: y = b2 + W @ b1 ----------------
__global__ __launch_bounds__(256) void k_bias_fold(const float* __restrict__ W,
                                                   const float* __restrict__ b1,
                                                   const float* __restrict__ b2,
                                                   float* __restrict__ y) {
    int row = blockIdx.x * 4 + (threadIdx.x >> 6);
    int lane = threadIdx.x & 63;
    const float* wr = W + (long)row * 1024;
    float s = 0.f;
    for (int k = lane; k < 1024; k += 64) s += wr[k] * b1[k];
#pragma unroll
    for (int o = 32; o >= 1; o >>= 1) s += __shfl_xor(s, o);
    if (lane == 0) y[row] = b2[row] + s;
}

// ---------------- high-precision split-bf16 GEMM ----------------
enum { HP_SPLIT = 0, HP_F32 = 1, HP_SPLIT_HEADS = 2 };

template<int MODE>
__global__ __launch_bounds__(256)
void gemm_hp(const bf16* __restrict__ Ah, const bf16* __restrict__ Al, int lda, long sAz,
             const bf16* __restrict__ Bh, const bf16* __restrict__ Bl, int ldb, long sBz,
             void* __restrict__ Chv, bf16* __restrict__ Cl, int ldc, long sCz,
             const float* __restrict__ bias, float alpha, int M, int N, int K) {
    __shared__ alignas(16) bf16 sAh[128 * 32];
    __shared__ alignas(16) bf16 sAl[128 * 32];
    __shared__ alignas(16) bf16 sBh[128 * 32];
    __shared__ alignas(16) bf16 sBl[128 * 32];
    const int bm = blockIdx.y, bn = blockIdx.x, z = blockIdx.z;
    const int tid  = threadIdx.x;
    const int lane = tid & 63, wave = tid >> 6;
    const int quad = lane >> 4, l16 = lane & 15;
    const int wr = wave >> 1, wc = wave & 1;
    const int sr = tid >> 2;
    const int sc = (tid & 3) * 8;

    int arow0 = min(bm * 128 + sr, M - 1);
    int arow1 = min(bm * 128 + sr + 64, M - 1);
    int brow0 = min(bn * 128 + sr, N - 1);
    int brow1 = min(bn * 128 + sr + 64, N - 1);

    const bf16* pAh0 = Ah + (long)z * sAz + (long)arow0 * lda + sc;
    const bf16* pAh1 = Ah + (long)z * sAz + (long)arow1 * lda + sc;
    const bf16* pAl0 = Al + (long)z * sAz + (long)arow0 * lda + sc;
    const bf16* pAl1 = Al + (long)z * sAz + (long)arow1 * lda + sc;
    const bf16* pBh0 = Bh + (long)z * sBz + (long)brow0 * ldb + sc;
    const bf16* pBh1 = Bh + (long)z * sBz + (long)brow1 * ldb + sc;
    const bf16* pBl0 = Bl + (long)z * sBz + (long)brow0 * ldb + sc;
    const bf16* pBl1 = Bl + (long)z * sBz + (long)brow1 * ldb + sc;
    const int wo = wave << 9;

    f32x4 acc[4][4];
#pragma unroll
    for (int i = 0; i < 4; i++)
#pragma unroll
        for (int j = 0; j < 4; j++) acc[i][j] = (f32x4){0.f, 0.f, 0.f, 0.f};

    for (int k0 = 0; k0 < K; k0 += 32) {
        __syncthreads();
        ld16(sAh + wo,        pAh0 + k0);
        ld16(sAh + 2048 + wo, pAh1 + k0);
        ld16(sAl + wo,        pAl0 + k0);
        ld16(sAl + 2048 + wo, pAl1 + k0);
        ld16(sBh + wo,        pBh0 + k0);
        ld16(sBh + 2048 + wo, pBh1 + k0);
        ld16(sBl + wo,        pBl0 + k0);
        ld16(sBl + 2048 + wo, pBl1 + k0);
        __syncthreads();
        bf16x8 ah[4], al[4], bh[4], bl[4];
#pragma unroll
        for (int i = 0; i < 4; i++) {
            int ro = (wr * 64 + i * 16 + l16) * 32 + quad * 8;
            ah[i] = *(const bf16x8*)&sAh[ro];
            al[i] = *(const bf16x8*)&sAl[ro];
        }
#pragma unroll
        for (int j = 0; j < 4; j++) {
            int ro = (wc * 64 + j * 16 + l16) * 32 + quad * 8;
            bh[j] = *(const bf16x8*)&sBh[ro];
            bl[j] = *(const bf16x8*)&sBl[ro];
        }
#pragma unroll
        for (int i = 0; i < 4; i++)
#pragma unroll
            for (int j = 0; j < 4; j++) {
                acc[i][j] = __builtin_amdgcn_mfma_f32_16x16x32_bf16(al[i], bh[j], acc[i][j], 0, 0, 0);
                acc[i][j] = __builtin_amdgcn_mfma_f32_16x16x32_bf16(ah[i], bl[j], acc[i][j], 0, 0, 0);
                acc[i][j] = __builtin_amdgcn_mfma_f32_16x16x32_bf16(ah[i], bh[j], acc[i][j], 0, 0, 0);
            }
    }

#pragma unroll
    for (int i = 0; i < 4; i++) {
        int mbase = bm * 128 + wr * 64 + i * 16 + quad * 4;
#pragma unroll
        for (int j = 0; j < 4; j++) {
            int n = bn * 128 + wc * 64 + j * 16 + l16;
            if (n < N) {
                float bv = bias ? bias[n] : 0.f;
#pragma unroll
                for (int r = 0; r < 4; r++) {
                    int m = mbase + r;
                    if (m < M) {
                        float v = alpha * acc[i][j][r] + bv;
                        if (MODE == HP_SPLIT) {
                            long cidx = (long)z * sCz + (long)m * ldc + n;
                            bf16 h = (bf16)v;
                            ((bf16*)Chv)[cidx] = h;
                            Cl[cidx] = (bf16)(v - (float)h);
                        } else if (MODE == HP_F32) {
                            long cidx = (long)z * sCz + (long)m * ldc + n;
                            ((float*)Chv)[cidx] = v;
                        } else {  // HP_SPLIT_HEADS: [slice=(b,h)][seq][64]
                            int slice = ((m >> 10) << 4) + (n >> 6);
                            long idx = (long)slice * 65536 + (long)(m & 1023) * 64 + (n & 63);
                            bf16 h = (bf16)v;
                            ((bf16*)Chv)[idx] = h;
                            Cl[idx] = (bf16)(v - (float)h);
                        }
                    }
                }
            }
        }
    }
}

// ---------------- MoE GEMM1 (batched over experts, GELU epilogue) ----------------
__global__ __launch_bounds__(256)
void gemm_moe1(const bf16* __restrict__ Ae, const bf16* __restrict__ ew1t,
               const float* __restrict__ eb1, bf16* __restrict__ Hp,
               const int* __restrict__ counts, const int* __restrict__ bases) {
    const int e = blockIdx.z;
    const int M = counts[e];
    const int bm = blockIdx.y, bn = blockIdx.x;
    if (bm * 128 >= M) return;
    const bf16* A = Ae + (long)bases[e] * 1024;
    const bf16* B = ew1t + (long)e * 4194304;
    bf16* C = Hp + (long)bases[e] * 4096;
    const float* bias = eb1 + e * 4096;

    __shared__ alignas(16) bf16 sA[128 * 32];
    __shared__ alignas(16) bf16 sB[128 * 32];
    const int tid  = threadIdx.x;
    const int lane = tid & 63, wave = tid >> 6;
    const int quad = lane >> 4, l16 = lane & 15;
    const int wr = wave >> 1, wc = wave & 1;
    const int sr = tid >> 2;
    const int sc = (tid & 3) * 8;

    int arow0 = min(bm * 128 + sr, M - 1);
    int arow1 = min(bm * 128 + sr + 64, M - 1);
    int brow0 = bn * 128 + sr;
    const bf16* pA0 = A + (long)arow0 * 1024 + sc;
    const bf16* pA1 = A + (long)arow1 * 1024 + sc;
    const bf16* pB0 = B + (long)brow0 * 1024 + sc;
    const bf16* pB1 = B + (long)(brow0 + 64) * 1024 + sc;
    const int wo = wave << 9;

    f32x4 acc[4][4];
#pragma unroll
    for (int i = 0; i < 4; i++)
#pragma unroll
        for (int j = 0; j < 4; j++) acc[i][j] = (f32x4){0.f, 0.f, 0.f, 0.f};

    for (int k0 = 0; k0 < 1024; k0 += 32) {
        __syncthreads();
        ld16(sA + wo,        pA0 + k0);
        ld16(sA + 2048 + wo, pA1 + k0);
        ld16(sB + wo,        pB0 + k0);
        ld16(sB + 2048 + wo, pB1 + k0);
        __syncthreads();
        bf16x8 af[4], bfr[4];
#pragma unroll
        for (int i = 0; i < 4; i++)
            af[i] = *(const bf16x8*)&sA[(wr * 64 + i * 16 + l16) * 32 + quad * 8];
#pragma unroll
        for (int j = 0; j < 4; j++)
            bfr[j] = *(const bf16x8*)&sB[(wc * 64 + j * 16 + l16) * 32 + quad * 8];
#pragma unroll
        for (int i = 0; i < 4; i++)
#pragma unroll
            for (int j = 0; j < 4; j++)
                acc[i][j] = __builtin_amdgcn_mfma_f32_16x16x32_bf16(af[i], bfr[j], acc[i][j], 0, 0, 0);
    }

#pragma unroll
    for (int i = 0; i < 4; i++) {
        int mbase = bm * 128 + wr * 64 + i * 16 + quad * 4;
#pragma unroll
        for (int j = 0; j < 4; j++) {
            int n = bn * 128 + wc * 64 + j * 16 + l16;
            float bv = bias[n];
#pragma unroll
            for (int r = 0; r < 4; r++) {
                int m = mbase + r;
                if (m < M) {
                    float v = acc[i][j][r] + bv;
                    float g = 0.5f * v * (1.f + erff(v * 0.70710678118654752f));
                    C[(long)m * 4096 + n] = (bf16)g;
                }
            }
        }
    }
}

// ---------------- MoE GEMM2 (batched, scatter atomicAdd epilogue) ----------------
__global__ __launch_bounds__(256)
void gemm_moe2(const bf16* __restrict__ Hp, const bf16* __restrict__ ew2t,
               const float* __restrict__ eb2, float* __restrict__ moe_out,
               const int* __restrict__ counts, const int* __restrict__ bases,
               const int* __restrict__ tok, const float* __restrict__ combine) {
    const int e = blockIdx.z;
    const int M = counts[e];
    const int bm = blockIdx.y, bn = blockIdx.x;
    if (bm * 128 >= M) return;
    const bf16* A = Hp + (long)bases[e] * 4096;
    const bf16* B = ew2t + (long)e * 4194304;
    const float* bias = eb2 + e * 1024;
    const int* etok = tok + e * 4096;

    __shared__ alignas(16) bf16 sA[128 * 32];
    __shared__ alignas(16) bf16 sB[128 * 32];
    const int tid  = threadIdx.x;
    const int lane = tid & 63, wave = tid >> 6;
    const int quad = lane >> 4, l16 = lane & 15;
    const int wr = wave >> 1, wc = wave & 1;
    const int sr = tid >> 2;
    const int sc = (tid & 3) * 8;

    int arow0 = min(bm * 128 + sr, M - 1);
    int arow1 = min(bm * 128 + sr + 64, M - 1);
    int brow0 = bn * 128 + sr;
    const bf16* pA0 = A + (long)arow0 * 4096 + sc;
    const bf16* pA1 = A + (long)arow1 * 4096 + sc;
    const bf16* pB0 = B + (long)brow0 * 4096 + sc;
    const bf16* pB1 = B + (long)(brow0 + 64) * 4096 + sc;
    const int wo = wave << 9;

    f32x4 acc[4][4];
#pragma unroll
    for (int i = 0; i < 4; i++)
#pragma unroll
        for (int j = 0; j < 4; j++) acc[i][j] = (f32x4){0.f, 0.f, 0.f, 0.f};

    for (int k0 = 0; k0 < 4096; k0 += 32) {
        __syncthreads();
        ld16(sA + wo,        pA0 + k0);
        ld16(sA + 2048 + wo, pA1 + k0);
        ld16(sB + wo,        pB0 + k0);
        ld16(sB + 2048 + wo, pB1 + k0);
        __syncthreads();
        bf16x8 af[4], bfr[4];
#pragma unroll
        for (int i = 0; i < 4; i++)
            af[i] = *(const bf16x8*)&sA[(wr * 64 + i * 16 + l16) * 32 + quad * 8];
#pragma unroll
        for (int j = 0; j < 4; j++)
            bfr[j] = *(const bf16x8*)&sB[(wc * 64 + j * 16 + l16) * 32 + quad * 8];
#pragma unroll
        for (int i = 0; i < 4; i++)
#pragma unroll
            for (int j = 0; j < 4; j++)
                acc[i][j] = __builtin_amdgcn_mfma_f32_16x16x32_bf16(af[i], bfr[j], acc[i][j], 0, 0, 0);
    }

#pragma unroll
    for (int i = 0; i < 4; i++) {
        int mbase = bm * 128 + wr * 64 + i * 16 + quad * 4;
#pragma unroll
        for (int j = 0; j < 4; j++) {
            int n = bn * 128 + wc * 64 + j * 16 + l16;
            float bv = bias[n];
#pragma unroll
            for (int r = 0; r < 4; r++) {
                int m = mbase + r;
                if (m < M) {
                    int t = etok[m];
                    float s = combine[t * 8 + e];
                    atomicAdd(&moe_out[(long)t * 1024 + n], s * (acc[i][j][r] + bv));
                }
            }
        }
    }
}

// ---------------- per-slice V transpose: VH [b*1024+q][h*64+d] -> VT [s][d][seq] ----------------
__global__ __launch_bounds__(256) void k_vsplit(const bf16* __restrict__ VH_h,
                                                const bf16* __restrict__ VH_l,
                                                bf16* __restrict__ VT_h,
                                                bf16* __restrict__ VT_l) {
    __shared__ bf16 th[64][65];
    __shared__ bf16 tl[64][65];
    int s = blockIdx.y, q0 = blockIdx.x * 64;
    int b = s >> 4, h = s & 15;
    long ibase = ((long)(b * 1024 + q0)) * 1024 + h * 64;
    for (int i = threadIdx.x; i < 4096; i += 256) {
        int q = i >> 6, d = i & 63;
        th[q][d] = VH_h[ibase + (long)q * 1024 + d];
        tl[q][d] = VH_l[ibase + (long)q * 1024 + d];
    }
    __syncthreads();
    long obase = (long)s * 65536 + q0;
    for (int i = threadIdx.x; i < 4096; i += 256) {
        int d = i >> 6, q = i & 63;
        VT_h[obase + (long)d * 1024 + q] = th[q][d];
        VT_l[obase + (long)d * 1024 + q] = tl[q][d];
    }
}

// ---------------- O reassembly: Op [s][q][64] -> O [t][1024] ----------------
__global__ __launch_bounds__(256) void k_ocopy(const bf16* __restrict__ Op_h,
                                               const bf16* __restrict__ Op_l,
                                               bf16* __restrict__ O_h,
                                               bf16* __restrict__ O_l) {
    int t = blockIdx.x * 4 + (threadIdx.x >> 6);
    int lane = threadIdx.x & 63;
    int b = t >> 10, q = t & 1023;
    int h = lane >> 2, dd = (lane & 3) * 16;
    long src = ((long)(b * 16 + h)) * 65536 + (long)q * 64 + dd;
    long dst = (long)t * 1024 + h * 64 + dd;
    *(bf16x8*)(O_h + dst)     = *(const bf16x8*)(Op_h + src);
    *(bf16x8*)(O_h + dst + 8) = *(const bf16x8*)(Op_h + src + 8);
    *(bf16x8*)(O_l + dst)     = *(const bf16x8*)(Op_l + src);
    *(bf16x8*)(O_l + dst + 8) = *(const bf16x8*)(Op_l + src + 8);
}

// ---------------- gather expert rows (packed) ----------------
__global__ __launch_bounds__(256) void k_gather(const bf16* __restrict__ Xb,
                                                const int* __restrict__ tok,
                                                const int* __restrict__ counts,
                                                const int* __restrict__ bases,
                                                bf16* __restrict__ Ae) {
    int e = blockIdx.y;
    int cnt = counts[e];
    long base = bases[e];
    for (int i = blockIdx.x; i < cnt; i += gridDim.x) {
        int t = tok[e * 4096 + i];
        const bf16x4* src = (const bf16x4*)(Xb + (long)t * 1024);
        bf16x4* dst = (bf16x4*)(Ae + (base + i) * 1024);
        dst[threadIdx.x] = src[threadIdx.x];
    }
}

// ---------------- in-place softmax on split rows ----------------
__global__ __launch_bounds__(256) void k_softmax_ip(bf16* __restrict__ Sh,
                                                    bf16* __restrict__ Sl) {
    int row = blockIdx.x * 4 + (threadIdx.x >> 6);
    int lane = threadIdx.x & 63;
    long o = (long)row * 1024 + lane * 16;
    bf16x8 h0 = *(const bf16x8*)(Sh + o), h1 = *(const bf16x8*)(Sh + o + 8);
    bf16x8 l0 = *(const bf16x8*)(Sl + o), l1 = *(const bf16x8*)(Sl + o + 8);
    float v[16];
#pragma unroll
    for (int i = 0; i < 8; i++) {
        v[i] = (float)h0[i] + (float)l0[i];
        v[8 + i] = (float)h1[i] + (float)l1[i];
    }
    float mx = v[0];
#pragma unroll
    for (int i = 1; i < 16; i++) mx = fmaxf(mx, v[i]);
#pragma unroll
    for (int of = 32; of >= 1; of >>= 1) mx = fmaxf(mx, __shfl_xor(mx, of));
    float s = 0.f;
#pragma unroll
    for (int i = 0; i < 16; i++) { v[i] = expf(v[i] - mx); s += v[i]; }
#pragma unroll
    for (int of = 32; of >= 1; of >>= 1) s += __shfl_xor(s, of);
    float inv = 1.f / s;
#pragma unroll
    for (int i = 0; i < 8; i++) {
        float a = v[i] * inv;
        h0[i] = (bf16)a; l0[i] = (bf16)(a - (float)h0[i]);
        float b = v[8 + i] * inv;
        h1[i] = (bf16)b; l1[i] = (bf16)(b - (float)h1[i]);
    }
    *(bf16x8*)(Sh + o) = h0;  *(bf16x8*)(Sh + o + 8) = h1;
    *(bf16x8*)(Sl + o) = l0;  *(bf16x8*)(Sl + o + 8) = l1;
}

// ---------------- layernorm ----------------
__global__ __launch_bounds__(256) void k_ln(const float* __restrict__ xin,
                                            const float* __restrict__ resid,
                                            const float* __restrict__ g,
                                            const float* __restrict__ bb,
                                            float* __restrict__ outf,
                                            bf16* __restrict__ outb) {
    int row = blockIdx.x * 4 + (threadIdx.x >> 6);
    int lane = threadIdx.x & 63;
    long base = (long)row * 1024 + lane * 16;
    float v[16];
#pragma unroll
    for (int i = 0; i < 16; i += 4) {
        f32x4 a = *(const f32x4*)(xin + base + i);
        if (resid) { f32x4 r4 = *(const f32x4*)(resid + base + i); a += r4; }
        v[i] = a[0]; v[i + 1] = a[1]; v[i + 2] = a[2]; v[i + 3] = a[3];
    }
    float s = 0.f;
#pragma unroll
    for (int i = 0; i < 16; i++) s += v[i];
#pragma unroll
    for (int o = 32; o >= 1; o >>= 1) s += __shfl_xor(s, o);
    float mean = s * (1.f / 1024.f);
    float vs = 0.f;
#pragma unroll
    for (int i = 0; i < 16; i++) { float d = v[i] - mean; vs += d * d; }
#pragma unroll
    for (int o = 32; o >= 1; o >>= 1) vs += __shfl_xor(vs, o);
    float inv = 1.f / sqrtf(vs * (1.f / 1024.f) + 1e-5f);
    const float* gp = g + lane * 16;
    const float* bp = bb + lane * 16;
#pragma unroll
    for (int i = 0; i < 16; i++) {
        float o = (v[i] - mean) * inv * gp[i] + bp[i];
        if (outf) outf[base + i] = o;
        if (outb) outb[base + i] = (bf16)o;
    }
}

// ---------------- gating (no routing atomics) ----------------
__global__ __launch_bounds__(256) void k_gate(const float* __restrict__ X,
                                              const float* __restrict__ Wg,
                                              float* __restrict__ combine,
                                              float* __restrict__ partials) {
    __shared__ float sm[16];
    if (threadIdx.x < 16) sm[threadIdx.x] = 0.f;
    __syncthreads();
    int t = blockIdx.x * 4 + (threadIdx.x >> 6);
    int lane = threadIdx.x & 63;
    const float* x = X + (long)t * 1024;
    float acc[8] = {0.f, 0.f, 0.f, 0.f, 0.f, 0.f, 0.f, 0.f};
    for (int i = lane; i < 1024; i += 64) {
        float xv = x[i];
        const float* w = Wg + i * 8;
#pragma unroll
        for (int e = 0; e < 8; e++) acc[e] += xv * w[e];
    }
#pragma unroll
    for (int e = 0; e < 8; e++)
#pragma unroll
        for (int o = 32; o >= 1; o >>= 1) acc[e] += __shfl_xor(acc[e], o);
    if (lane == 0) {
        float mx = acc[0];
#pragma unroll
        for (int e = 1; e < 8; e++) mx = fmaxf(mx, acc[e]);
        float p[8], s = 0.f;
#pragma unroll
        for (int e = 0; e < 8; e++) { p[e] = expf(acc[e] - mx); s += p[e]; }
        float invs = 1.f / s;
#pragma unroll
        for (int e = 0; e < 8; e++) p[e] *= invs;
        float b1 = -1.f, b2 = -1.f, b3 = -1.f; int i1 = 0, i2 = 0, i3 = 0;
#pragma unroll
        for (int e = 0; e < 8; e++) {
            float pe = p[e];
            if (pe > b1)      { b3 = b2; i3 = i2; b2 = b1; i2 = i1; b1 = pe; i1 = e; }
            else if (pe > b2) { b3 = b2; i3 = i2; b2 = pe; i2 = e; }
            else if (pe > b3) { b3 = pe; i3 = e; }
        }
        float c[8] = {0.f, 0.f, 0.f, 0.f, 0.f, 0.f, 0.f, 0.f};
        c[i1] = b1;
        if (b2 >= THRESH_C) c[i2] = b2;
        if (b3 >= THRESH_C) c[i3] = b3;
        float* co = combine + (long)t * 8;
#pragma unroll
        for (int e = 0; e < 8; e++) co[e] = c[e];
#pragma unroll
        for (int e = 0; e < 8; e++) {
            atomicAdd(&sm[e], p[e]);
            if (c[e] > 0.f) atomicAdd(&sm[8 + e], 1.f);
        }
    }
    __syncthreads();
    if (threadIdx.x < 16) partials[(long)blockIdx.x * 16 + threadIdx.x] = sm[threadIdx.x];
}

// ---------------- deterministic routing (single block, prefix sums) ----------------
__global__ __launch_bounds__(256) void k_route(const float* __restrict__ combine,
                                               int* __restrict__ counts,
                                               int* __restrict__ bases,
                                               int* __restrict__ tok) {
    __shared__ int scan[256];
    __shared__ int ebase;
    int tid = threadIdx.x;
    if (tid == 0) ebase = 0;
    __syncthreads();
    for (int e = 0; e < 8; e++) {
        int pred[16]; int cnt = 0;
#pragma unroll
        for (int j = 0; j < 16; j++) {
            int t = tid * 16 + j;
            pred[j] = combine[t * 8 + e] > 0.f ? 1 : 0;
            cnt += pred[j];
        }
        scan[tid] = cnt;
        __syncthreads();
        for (int off = 1; off < 256; off <<= 1) {
            int v = (tid >= off) ? scan[tid - off] : 0;
            __syncthreads();
            scan[tid] += v;
            __syncthreads();
        }
        int o = e * 4096 + scan[tid] - cnt;
        int total = scan[255];
#pragma unroll
        for (int j = 0; j < 16; j++) {
            if (pred[j]) tok[o++] = tid * 16 + j;
        }
        if (tid == 0) { counts[e] = total; bases[e] = ebase; ebase += total; }
        __syncthreads();
    }
}

// ---------------- aux reduce ----------------
__global__ __launch_bounds__(256) void k_aux(const float* __restrict__ partials, int nblocks,
                                             float* __restrict__ auxout) {
    __shared__ float red[256];
    int tid = threadIdx.x;
    int e = tid & 15, grp = tid >> 4;
    float s = 0.f;
    for (int b = grp; b < nblocks; b += 16) s += partials[(long)b * 16 + e];
    red[tid] = s;
    __syncthreads();
    if (grp == 0) {
        float tot = 0.f;
        for (int g2 = 0; g2 < 16; g2++) tot += red[g2 * 16 + e];
        red[tid] = tot;
    }
    __syncthreads();
    if (tid == 0) {
        float s2 = 0.f;
        for (int e2 = 0; e2 < 8; e2++)
            s2 += (red[8 + e2] * (1.f / 4096.f)) * (red[e2] * (1.f / 4096.f));
        auxout[0] = COEF_C * 8.f * s2;
    }
}

// ---------------- host ----------------
extern "C" void kernel_launch(void* const* d_in, const int* in_sizes, int n_in,
                              void* d_out, int out_size, void* d_ws, size_t ws_size,
                              hipStream_t stream) {
    const float* query     = (const float*)d_in[0];
    const float* key_value = (const float*)d_in[1];
    const float* Wq   = (const float*)d_in[2];
    const float* bq   = (const float*)d_in[3];
    const float* Wk   = (const float*)d_in[4];
    const float* bk   = (const float*)d_in[5];
    const float* Wv   = (const float*)d_in[6];
    const float* bv   = (const float*)d_in[7];
    const float* W_in = (const float*)d_in[8];
    const float* b_in = (const float*)d_in[9];
    const float* W_out = (const float*)d_in[10];
    const float* b_out = (const float*)d_in[11];
    const float* Wa   = (const float*)d_in[12];
    const float* ba   = (const float*)d_in[13];
    const float* ln1_g = (const float*)d_in[14];
    const float* ln1_b = (const float*)d_in[15];
    const float* Wg   = (const float*)d_in[16];
    const float* ew1  = (const float*)d_in[17];
    const float* eb1  = (const float*)d_in[18];
    const float* ew2  = (const float*)d_in[19];
    const float* eb2  = (const float*)d_in[20];
    const float* ln2_g = (const float*)d_in[21];
    const float* ln2_b = (const float*)d_in[22];

    const size_t MBY = 1ull << 20;
    const long MB1 = 1024L * 1024L;
    char* ws = (char*)d_ws;

    // phase-aliased workspace map (peak ~345 MB)
    bf16* Sh   = (bf16*)(ws + 0 * MBY);      // attn: 64MB (32 slices split-hi)
    bf16* Sl   = (bf16*)(ws + 64 * MBY);     // attn: 64MB
    bf16* ew1t = (bf16*)(ws + 0 * MBY);      // MoE phase
    bf16* ew2t = (bf16*)(ws + 64 * MBY);
    // prep region [128,192)
    bf16* Win_h = (bf16*)(ws + 128 * MBY), *Win_l = (bf16*)(ws + 134 * MBY);
    bf16* Wa_h  = (bf16*)(ws + 140 * MBY), *Wa_l  = (bf16*)(ws + 142 * MBY);
    bf16* WqT_h = (bf16*)(ws + 144 * MBY), *WqT_l = (bf16*)(ws + 146 * MBY);
    bf16* WkT_h = (bf16*)(ws + 148 * MBY), *WkT_l = (bf16*)(ws + 150 * MBY);
    bf16* WvT_h = (bf16*)(ws + 152 * MBY), *WvT_l = (bf16*)(ws + 154 * MBY);
    bf16* WoT_h = (bf16*)(ws + 156 * MBY), *WoT_l = (bf16*)(ws + 158 * MBY);
    bf16* Xq_h  = (bf16*)(ws + 160 * MBY), *Xq_l  = (bf16*)(ws + 168 * MBY);
    bf16* Xkv_h = (bf16*)(ws + 176 * MBY), *Xkv_l = (bf16*)(ws + 184 * MBY);
    // attn-phase aliases
    bf16* O_h  = (bf16*)(ws + 160 * MBY), *O_l  = (bf16*)(ws + 168 * MBY);  // over dead Xq
    bf16* QHp_h = (bf16*)(ws + 192 * MBY), *QHp_l = (bf16*)(ws + 200 * MBY);
    bf16* KHp_h = (bf16*)(ws + 208 * MBY), *KHp_l = (bf16*)(ws + 216 * MBY);
    bf16* VH_h  = (bf16*)(ws + 224 * MBY), *VH_l  = (bf16*)(ws + 232 * MBY);
    bf16* VTp_h = (bf16*)(ws + 240 * MBY), *VTp_l = (bf16*)(ws + 248 * MBY);
    bf16* Op_h  = (bf16*)(ws + 256 * MBY), *Op_l  = (bf16*)(ws + 264 * MBY);
    float* Xf   = (float*)(ws + 256 * MBY);   // over dead Op, [256,272)
    float* Af   = (float*)(ws + 272 * MBY);   // [272,288)
    // MoE phase
    bf16* Ae      = (bf16*)(ws + 128 * MBY);  // packed, worst 24MB [128,152)
    bf16* Hp      = (bf16*)(ws + 152 * MBY);  // packed, worst 96MB [152,248)
    float* moe_out = (float*)(ws + 272 * MBY);// over dead Af
    bf16* Xb   = (bf16*)(ws + 320 * MBY);     // [320,328)
    bf16* Weq_h = (bf16*)(ws + 328 * MBY), *Weq_l = (bf16*)(ws + 330 * MBY);
    bf16* Wek_h = (bf16*)(ws + 332 * MBY), *Wek_l = (bf16*)(ws + 334 * MBY);
    bf16* Wev_h = (bf16*)(ws + 336 * MBY), *Wev_l = (bf16*)(ws + 338 * MBY);
    bf16* Woa_h = (bf16*)(ws + 340 * MBY), *Woa_l = (bf16*)(ws + 342 * MBY);
    float* combine  = (float*)(ws + 344 * MBY);
    float* partials = (float*)(ws + 344 * MBY + 128 * 1024);
    float* beff     = (float*)(ws + 344 * MBY + 192 * 1024);
    float* b_oa     = (float*)(ws + 344 * MBY + 208 * 1024);
    int*   counts   = (int*)  (ws + 344 * MBY + 212 * 1024);
    int*   bases    = (int*)  (ws + 344 * MBY + 213 * 1024);
    int*   tok      = (int*)  (ws + 344 * MBY + 214 * 1024);

    dim3 blk(256);

    // ---- prep: conversions + splits ----
    k_f32_to_split<<<4096, blk, 0, stream>>>(query, Xq_h, Xq_l, 4L * MB1);
    k_f32_to_split<<<4096, blk, 0, stream>>>(key_value, Xkv_h, Xkv_l, 4L * MB1);
    k_f32_to_split<<<3072, blk, 0, stream>>>(W_in, Win_h, Win_l, 3L * MB1);
    k_f32_to_split<<<1024, blk, 0, stream>>>(Wa, Wa_h, Wa_l, MB1);
    k_transpose_f32_split<<<dim3(16, 16), blk, 0, stream>>>(Wq, WqT_h, WqT_l, 1024, 1024);
    k_transpose_f32_split<<<dim3(16, 16), blk, 0, stream>>>(Wk, WkT_h, WkT_l, 1024, 1024);
    k_transpose_f32_split<<<dim3(16, 16), blk, 0, stream>>>(Wv, WvT_h, WvT_l, 1024, 1024);
    k_transpose_f32_split<<<dim3(16, 16), blk, 0, stream>>>(W_out, WoT_h, WoT_l, 1024, 1024);
    k_bias_fold<<<256, blk, 0, stream>>>(W_in,           bq, b_in,        beff);
    k_bias_fold<<<256, blk, 0, stream>>>(W_in + MB1,     bk, b_in + 1024, beff + 1024);
    k_bias_fold<<<256, blk, 0, stream>>>(W_in + 2 * MB1, bv, b_in + 2048, beff + 2048);
    k_bias_fold<<<256, blk, 0, stream>>>(Wa, b_out, ba, b_oa);

    // ---- weight folds ----
    dim3 gW(8, 8, 1);
    gemm_hp<HP_SPLIT><<<gW, blk, 0, stream>>>(Win_h, Win_l, 1024, 0, WqT_h, WqT_l, 1024, 0,
                                              Weq_h, Weq_l, 1024, 0, nullptr, 1.f, 1024, 1024, 1024);
    gemm_hp<HP_SPLIT><<<gW, blk, 0, stream>>>(Win_h + MB1, Win_l + MB1, 1024, 0, WkT_h, WkT_l, 1024, 0,
                                              Wek_h, Wek_l, 1024, 0, nullptr, 1.f, 1024, 1024, 1024);
    gemm_hp<HP_SPLIT><<<gW, blk, 0, stream>>>(Win_h + 2 * MB1, Win_l + 2 * MB1, 1024, 0, WvT_h, WvT_l, 1024, 0,
                                              Wev_h, Wev_l, 1024, 0, nullptr, 1.f, 1024, 1024, 1024);
    gemm_hp<HP_SPLIT><<<gW, blk, 0, stream>>>(Wa_h, Wa_l, 1024, 0, WoT_h, WoT_l, 1024, 0,
                                              Woa_h, Woa_l, 1024, 0, nullptr, 1.f, 1024, 1024, 1024);

    // ---- projections: Q/K to head-split layout, V to token layout ----
    dim3 gP(8, 32, 1);
    gemm_hp<HP_SPLIT_HEADS><<<gP, blk, 0, stream>>>(Xq_h, Xq_l, 1024, 0, Weq_h, Weq_l, 1024, 0,
                                                    QHp_h, QHp_l, 0, 0, beff, 1.f, 4096, 1024, 1024);
    gemm_hp<HP_SPLIT_HEADS><<<gP, blk, 0, stream>>>(Xkv_h, Xkv_l, 1024, 0, Wek_h, Wek_l, 1024, 0,
                                                    KHp_h, KHp_l, 0, 0, beff + 1024, 1.f, 4096, 1024, 1024);
    gemm_hp<HP_SPLIT><<<gP, blk, 0, stream>>>(Xkv_h, Xkv_l, 1024, 0, Wev_h, Wev_l, 1024, 0,
                                              VH_h, VH_l, 1024, 0, beff + 2048, 1.f, 4096, 1024, 1024);
    k_vsplit<<<dim3(16, 64), blk, 0, stream>>>(VH_h, VH_l, VTp_h, VTp_l);

    // ---- attention: 2 halves of 32 (b,h) slices ----
    for (int half = 0; half < 2; half++) {
        long so = (long)half * 32 * 65536;
        gemm_hp<HP_SPLIT><<<dim3(8, 8, 32), blk, 0, stream>>>(
            QHp_h + so, QHp_l + so, 64, 65536,
            KHp_h + so, KHp_l + so, 64, 65536,
            Sh, Sl, 1024, MB1, nullptr, 0.125f, 1024, 1024, 64);
        k_softmax_ip<<<8192, blk, 0, stream>>>(Sh, Sl);
        gemm_hp<HP_SPLIT><<<dim3(1, 8, 32), blk, 0, stream>>>(
            Sh, Sl, 1024, MB1,
            VTp_h + so, VTp_l + so, 1024, 65536,
            Op_h + so, Op_l + so, 64, 65536, nullptr, 1.f, 1024, 64, 1024);
    }
    k_ocopy<<<1024, blk, 0, stream>>>(Op_h, Op_l, O_h, O_l);

    // ---- out-proj+adapter (folded) + LN1 + gate + route ----
    gemm_hp<HP_F32><<<gP, blk, 0, stream>>>(O_h, O_l, 1024, 0, Woa_h, Woa_l, 1024, 0,
                                            Af, nullptr, 1024, 0, b_oa, 1.f, 4096, 1024, 1024);
    k_ln<<<1024, blk, 0, stream>>>(Af, query, ln1_g, ln1_b, Xf, Xb);
    k_gate<<<1024, blk, 0, stream>>>(Xf, Wg, combine, partials);
    k_route<<<1, blk, 0, stream>>>(combine, counts, bases, tok);
    k_gather<<<dim3(512, 8), blk, 0, stream>>>(Xb, tok, counts, bases, Ae);

    // ---- expert weight transposes (region freed after attention) ----
    k_transpose_ew<<<dim3(64, 16, 8), blk, 0, stream>>>(ew1, ew1t, 1024, 4096);
    k_transpose_ew<<<dim3(16, 64, 8), blk, 0, stream>>>(ew2, ew2t, 4096, 1024);

    // ---- batched routed MoE ----
    hipMemsetAsync(moe_out, 0, (long)4096 * 1024 * 4, stream);
    gemm_moe1<<<dim3(32, 32, 8), blk, 0, stream>>>(Ae, ew1t, eb1, Hp, counts, bases);
    gemm_moe2<<<dim3(8, 32, 8), blk, 0, stream>>>(Hp, ew2t, eb2, moe_out, counts, bases, tok, combine);

    // ---- LN2 + aux ----
    k_ln<<<1024, blk, 0, stream>>>(moe_out, Xf, ln2_g, ln2_b, (float*)d_out, nullptr);
    k_aux<<<1, blk, 0, stream>>>(partials, 1024, (float*)d_out + (out_size - 1));
}

// Round 5
// 1825.349 us; speedup vs baseline: 1.8553x; 1.0717x over previous
//
#include <hip/hip_runtime.h>
#include <math.h>

#define THRESH_C 0.05f
#define COEF_C   0.01f

typedef __bf16 bf16;
typedef __bf16 bf16x8 __attribute__((ext_vector_type(8)));
typedef __bf16 bf16x4 __attribute__((ext_vector_type(4)));
typedef float  f32x4  __attribute__((ext_vector_type(4)));

// async global->LDS, 16B per lane, dest = wave-uniform base + lane*16
__device__ __forceinline__ void ld16(void* lds_base, const void* g) {
    __builtin_amdgcn_global_load_lds(
        (const __attribute__((address_space(1))) void*)g,
        (__attribute__((address_space(3))) void*)lds_base,
        16, 0, 0);
}

// ---------------- f32 -> split (hi+lo bf16) ----------------
__global__ __launch_bounds__(256) void k_f32_to_split(const float* __restrict__ in,
                                                      bf16* __restrict__ hi,
                                                      bf16* __restrict__ lo, long n) {
    long i = ((long)blockIdx.x * 256 + threadIdx.x) * 4;
    if (i >= n) return;
    float4 v = *(const float4*)(in + i);
    bf16x4 h, l;
    h[0] = (bf16)v.x; l[0] = (bf16)(v.x - (float)h[0]);
    h[1] = (bf16)v.y; l[1] = (bf16)(v.y - (float)h[1]);
    h[2] = (bf16)v.z; l[2] = (bf16)(v.z - (float)h[2]);
    h[3] = (bf16)v.w; l[3] = (bf16)(v.w - (float)h[3]);
    *(bf16x4*)(hi + i) = h;
    *(bf16x4*)(lo + i) = l;
}

// ---------------- merged 4-way f32 transpose -> split (z picks source) ----------------
__global__ __launch_bounds__(256) void k_transpose4_split(const float* __restrict__ w0,
                                                          const float* __restrict__ w1,
                                                          const float* __restrict__ w2,
                                                          const float* __restrict__ w3,
                                                          bf16* __restrict__ oh,
                                                          bf16* __restrict__ ol) {
    __shared__ float t[64][65];
    int z = blockIdx.z;
    const float* in = (z == 0) ? w0 : (z == 1) ? w1 : (z == 2) ? w2 : w3;
    bf16* ohz = oh + (long)z * 1048576;
    bf16* olz = ol + (long)z * 1048576;
    int r0 = blockIdx.y * 64, c0 = blockIdx.x * 64;
    for (int i = threadIdx.x; i < 4096; i += 256) {
        int r = i >> 6, c = i & 63;
        t[r][c] = in[(long)(r0 + r) * 1024 + (c0 + c)];
    }
    __syncthreads();
    for (int i = threadIdx.x; i < 4096; i += 256) {
        int c = i >> 6, r = i & 63;
        float v = t[r][c];
        bf16 h = (bf16)v;
        long o = (long)(c0 + c) * 1024 + (r0 + r);
        ohz[o] = h;
        olz[o] = (bf16)(v - (float)h);
    }
}

// ---------------- expert weight transpose to bf16 ----------------
__global__ __launch_bounds__(256) void k_transpose_ew(const float* __restrict__ in,
                                                      bf16* __restrict__ out,
                                                      int R, int C) {
    __shared__ bf16 t[64][65];
    const float* ib = in + (long)blockIdx.z * R * C;
    bf16* ob = out + (long)blockIdx.z * R * C;
    int r0 = blockIdx.y * 64, c0 = blockIdx.x * 64;
    for (int i = threadIdx.x; i < 4096; i += 256) {
        int r = i >> 6, c = i & 63;
        t[r][c] = (bf16)ib[(long)(r0 + r) * C + (c0 + c)];
    }
    __syncthreads();
    for (int i = threadIdx.x; i < 4096; i += 256) {
        int c = i >> 6, r = i & 63;
        ob[(long)(c0 + c) * R + (r0 + r)] = t[r][c];
    }
}

// ---------------- merged bias folds: y_z = b2_z + W_z @ b1_z ----------------
__global__ __launch_bounds__(256) void k_bias_fold4(const float* __restrict__ W_in,
                                                    const float* __restrict__ Wa,
                                                    const float* __restrict__ bq,
                                                    const float* __restrict__ bk,
                                                    const float* __restrict__ bv,
                                                    const float* __restrict__ b_out,
                                                    const float* __restrict__ b_in,
                                                    const float* __restrict__ ba,
                                                    float* __restrict__ y) {
    int z = blockIdx.y;
    const float* W  = (z < 3) ? (W_in + (long)z * 1048576) : Wa;
    const float* b1 = (z == 0) ? bq : (z == 1) ? bk : (z == 2) ? bv : b_out;
    const float* b2 = (z < 3) ? (b_in + z * 1024) : ba;
    int row = blockIdx.x * 4 + (threadIdx.x >> 6);
    int lane = threadIdx.x & 63;
    const float* wr = W + (long)row * 1024;
    float s = 0.f;
    for (int k = lane; k < 1024; k += 64) s += wr[k] * b1[k];
#pragma unroll
    for (int o = 32; o >= 1; o >>= 1) s += __shfl_xor(s, o);
    if (lane == 0) y[z * 1024 + row] = b2[row] + s;
}

// ---------------- high-precision split-bf16 GEMM ----------------
enum { HP_SPLIT = 0, HP_F32 = 1, HP_SPLIT_HEADS = 2 };

template<int MODE>
__global__ __launch_bounds__(256)
void gemm_hp(const bf16* __restrict__ Ah, const bf16* __restrict__ Al, int lda, long sAz,
             const bf16* __restrict__ Bh, const bf16* __restrict__ Bl, int ldb, long sBz,
             void* __restrict__ Chv, bf16* __restrict__ Cl, int ldc, long sCz,
             const float* __restrict__ bias, float alpha, int M, int N, int K) {
    __shared__ alignas(16) bf16 sAh[128 * 32];
    __shared__ alignas(16) bf16 sAl[128 * 32];
    __shared__ alignas(16) bf16 sBh[128 * 32];
    __shared__ alignas(16) bf16 sBl[128 * 32];
    const int bm = blockIdx.y, bn = blockIdx.x, z = blockIdx.z;
    const int tid  = threadIdx.x;
    const int lane = tid & 63, wave = tid >> 6;
    const int quad = lane >> 4, l16 = lane & 15;
    const int wr = wave >> 1, wc = wave & 1;
    const int sr = tid >> 2;
    const int sc = (tid & 3) * 8;

    int arow0 = min(bm * 128 + sr, M - 1);
    int arow1 = min(bm * 128 + sr + 64, M - 1);
    int brow0 = min(bn * 128 + sr, N - 1);
    int brow1 = min(bn * 128 + sr + 64, N - 1);

    const bf16* pAh0 = Ah + (long)z * sAz + (long)arow0 * lda + sc;
    const bf16* pAh1 = Ah + (long)z * sAz + (long)arow1 * lda + sc;
    const bf16* pAl0 = Al + (long)z * sAz + (long)arow0 * lda + sc;
    const bf16* pAl1 = Al + (long)z * sAz + (long)arow1 * lda + sc;
    const bf16* pBh0 = Bh + (long)z * sBz + (long)brow0 * ldb + sc;
    const bf16* pBh1 = Bh + (long)z * sBz + (long)brow1 * ldb + sc;
    const bf16* pBl0 = Bl + (long)z * sBz + (long)brow0 * ldb + sc;
    const bf16* pBl1 = Bl + (long)z * sBz + (long)brow1 * ldb + sc;
    const int wo = wave << 9;

    f32x4 acc[4][4];
#pragma unroll
    for (int i = 0; i < 4; i++)
#pragma unroll
        for (int j = 0; j < 4; j++) acc[i][j] = (f32x4){0.f, 0.f, 0.f, 0.f};

    for (int k0 = 0; k0 < K; k0 += 32) {
        __syncthreads();
        ld16(sAh + wo,        pAh0 + k0);
        ld16(sAh + 2048 + wo, pAh1 + k0);
        ld16(sAl + wo,        pAl0 + k0);
        ld16(sAl + 2048 + wo, pAl1 + k0);
        ld16(sBh + wo,        pBh0 + k0);
        ld16(sBh + 2048 + wo, pBh1 + k0);
        ld16(sBl + wo,        pBl0 + k0);
        ld16(sBl + 2048 + wo, pBl1 + k0);
        __syncthreads();
        bf16x8 ah[4], al[4], bh[4], bl[4];
#pragma unroll
        for (int i = 0; i < 4; i++) {
            int ro = (wr * 64 + i * 16 + l16) * 32 + quad * 8;
            ah[i] = *(const bf16x8*)&sAh[ro];
            al[i] = *(const bf16x8*)&sAl[ro];
        }
#pragma unroll
        for (int j = 0; j < 4; j++) {
            int ro = (wc * 64 + j * 16 + l16) * 32 + quad * 8;
            bh[j] = *(const bf16x8*)&sBh[ro];
            bl[j] = *(const bf16x8*)&sBl[ro];
        }
#pragma unroll
        for (int i = 0; i < 4; i++)
#pragma unroll
            for (int j = 0; j < 4; j++) {
                acc[i][j] = __builtin_amdgcn_mfma_f32_16x16x32_bf16(al[i], bh[j], acc[i][j], 0, 0, 0);
                acc[i][j] = __builtin_amdgcn_mfma_f32_16x16x32_bf16(ah[i], bl[j], acc[i][j], 0, 0, 0);
                acc[i][j] = __builtin_amdgcn_mfma_f32_16x16x32_bf16(ah[i], bh[j], acc[i][j], 0, 0, 0);
            }
    }

#pragma unroll
    for (int i = 0; i < 4; i++) {
        int mbase = bm * 128 + wr * 64 + i * 16 + quad * 4;
#pragma unroll
        for (int j = 0; j < 4; j++) {
            int n = bn * 128 + wc * 64 + j * 16 + l16;
            if (n < N) {
                float bv = bias ? bias[n] : 0.f;
#pragma unroll
                for (int r = 0; r < 4; r++) {
                    int m = mbase + r;
                    if (m < M) {
                        float v = alpha * acc[i][j][r] + bv;
                        if (MODE == HP_SPLIT) {
                            long cidx = (long)z * sCz + (long)m * ldc + n;
                            bf16 h = (bf16)v;
                            ((bf16*)Chv)[cidx] = h;
                            Cl[cidx] = (bf16)(v - (float)h);
                        } else if (MODE == HP_F32) {
                            long cidx = (long)z * sCz + (long)m * ldc + n;
                            ((float*)Chv)[cidx] = v;
                        } else {  // HP_SPLIT_HEADS: [slice=(b,h)][seq][64]
                            int slice = ((m >> 10) << 4) + (n >> 6);
                            long idx = (long)slice * 65536 + (long)(m & 1023) * 64 + (n & 63);
                            bf16 h = (bf16)v;
                            ((bf16*)Chv)[idx] = h;
                            Cl[idx] = (bf16)(v - (float)h);
                        }
                    }
                }
            }
        }
    }
}

// ---------------- PV GEMM: per-slice P[1024x1024] @ V^T[64x1024]^T, 128x64 tiles ----------------
__global__ __launch_bounds__(256)
void gemm_pv(const bf16* __restrict__ Ph, const bf16* __restrict__ Pl,
             const bf16* __restrict__ Vh, const bf16* __restrict__ Vl,
             bf16* __restrict__ Oh, bf16* __restrict__ Ol) {
    __shared__ alignas(16) bf16 sAh[128 * 32];
    __shared__ alignas(16) bf16 sAl[128 * 32];
    __shared__ alignas(16) bf16 sBh[64 * 32];
    __shared__ alignas(16) bf16 sBl[64 * 32];
    const int bm = blockIdx.x, z = blockIdx.y;
    const int tid = threadIdx.x, lane = tid & 63, wave = tid >> 6;
    const int quad = lane >> 4, l16 = lane & 15;
    const int wr = wave & 1, wc = wave >> 1;   // 2 waves in M, 2 in N(32 each)
    const int sr = tid >> 2, sc = (tid & 3) * 8;

    const bf16* pA0h = Ph + (long)z * 1048576 + (long)(bm * 128 + sr) * 1024 + sc;
    const bf16* pA1h = pA0h + 64 * 1024;
    const bf16* pA0l = Pl + (long)z * 1048576 + (long)(bm * 128 + sr) * 1024 + sc;
    const bf16* pA1l = pA0l + 64 * 1024;
    const bf16* pB0h = Vh + (long)z * 65536 + (long)sr * 1024 + sc;
    const bf16* pB0l = Vl + (long)z * 65536 + (long)sr * 1024 + sc;
    const int wo = wave << 9;
    const int wob = wave << 7;   // 64x32 tile: 128 elements per wave... (see note)

    f32x4 acc[4][2];
#pragma unroll
    for (int i = 0; i < 4; i++)
#pragma unroll
        for (int j = 0; j < 2; j++) acc[i][j] = (f32x4){0.f, 0.f, 0.f, 0.f};

    for (int k0 = 0; k0 < 1024; k0 += 32) {
        __syncthreads();
        ld16(sAh + wo,        pA0h + k0);
        ld16(sAh + 2048 + wo, pA1h + k0);
        ld16(sAl + wo,        pA0l + k0);
        ld16(sAl + 2048 + wo, pA1l + k0);
        // B tile 64x32 = 4KB: one call, wave w covers rows 16w..16w+15 -> LDS base w*512 elems
        ld16(sBh + wo, pB0h + k0);
        ld16(sBl + wo, pB0l + k0);
        __syncthreads();
        bf16x8 ah[4], al[4], bh[2], bl[2];
#pragma unroll
        for (int i = 0; i < 4; i++) {
            int ro = (wr * 64 + i * 16 + l16) * 32 + quad * 8;
            ah[i] = *(const bf16x8*)&sAh[ro];
            al[i] = *(const bf16x8*)&sAl[ro];
        }
#pragma unroll
        for (int j = 0; j < 2; j++) {
            int ro = (wc * 32 + j * 16 + l16) * 32 + quad * 8;
            bh[j] = *(const bf16x8*)&sBh[ro];
            bl[j] = *(const bf16x8*)&sBl[ro];
        }
#pragma unroll
        for (int i = 0; i < 4; i++)
#pragma unroll
            for (int j = 0; j < 2; j++) {
                acc[i][j] = __builtin_amdgcn_mfma_f32_16x16x32_bf16(al[i], bh[j], acc[i][j], 0, 0, 0);
                acc[i][j] = __builtin_amdgcn_mfma_f32_16x16x32_bf16(ah[i], bl[j], acc[i][j], 0, 0, 0);
                acc[i][j] = __builtin_amdgcn_mfma_f32_16x16x32_bf16(ah[i], bh[j], acc[i][j], 0, 0, 0);
            }
    }

#pragma unroll
    for (int i = 0; i < 4; i++) {
        int mbase = bm * 128 + wr * 64 + i * 16 + quad * 4;
#pragma unroll
        for (int j = 0; j < 2; j++) {
            int n = wc * 32 + j * 16 + l16;
#pragma unroll
            for (int r = 0; r < 4; r++) {
                int m = mbase + r;
                long idx = (long)z * 65536 + (long)m * 64 + n;
                float v = acc[i][j][r];
                bf16 h = (bf16)v;
                Oh[idx] = h;
                Ol[idx] = (bf16)(v - (float)h);
            }
        }
    }
}

// ---------------- MoE GEMM1 (batched over experts, GELU epilogue) ----------------
__global__ __launch_bounds__(256)
void gemm_moe1(const bf16* __restrict__ Ae, const bf16* __restrict__ ew1t,
               const float* __restrict__ eb1, bf16* __restrict__ Hp,
               const int* __restrict__ counts, const int* __restrict__ bases) {
    const int e = blockIdx.z;
    const int M = counts[e];
    const int bm = blockIdx.y, bn = blockIdx.x;
    if (bm * 128 >= M) return;
    const bf16* A = Ae + (long)bases[e] * 1024;
    const bf16* B = ew1t + (long)e * 4194304;
    bf16* C = Hp + (long)bases[e] * 4096;
    const float* bias = eb1 + e * 4096;

    __shared__ alignas(16) bf16 sA[128 * 32];
    __shared__ alignas(16) bf16 sB[128 * 32];
    const int tid  = threadIdx.x;
    const int lane = tid & 63, wave = tid >> 6;
    const int quad = lane >> 4, l16 = lane & 15;
    const int wr = wave >> 1, wc = wave & 1;
    const int sr = tid >> 2;
    const int sc = (tid & 3) * 8;

    int arow0 = min(bm * 128 + sr, M - 1);
    int arow1 = min(bm * 128 + sr + 64, M - 1);
    int brow0 = bn * 128 + sr;
    const bf16* pA0 = A + (long)arow0 * 1024 + sc;
    const bf16* pA1 = A + (long)arow1 * 1024 + sc;
    const bf16* pB0 = B + (long)brow0 * 1024 + sc;
    const bf16* pB1 = B + (long)(brow0 + 64) * 1024 + sc;
    const int wo = wave << 9;

    f32x4 acc[4][4];
#pragma unroll
    for (int i = 0; i < 4; i++)
#pragma unroll
        for (int j = 0; j < 4; j++) acc[i][j] = (f32x4){0.f, 0.f, 0.f, 0.f};

    for (int k0 = 0; k0 < 1024; k0 += 32) {
        __syncthreads();
        ld16(sA + wo,        pA0 + k0);
        ld16(sA + 2048 + wo, pA1 + k0);
        ld16(sB + wo,        pB0 + k0);
        ld16(sB + 2048 + wo, pB1 + k0);
        __syncthreads();
        bf16x8 af[4], bfr[4];
#pragma unroll
        for (int i = 0; i < 4; i++)
            af[i] = *(const bf16x8*)&sA[(wr * 64 + i * 16 + l16) * 32 + quad * 8];
#pragma unroll
        for (int j = 0; j < 4; j++)
            bfr[j] = *(const bf16x8*)&sB[(wc * 64 + j * 16 + l16) * 32 + quad * 8];
#pragma unroll
        for (int i = 0; i < 4; i++)
#pragma unroll
            for (int j = 0; j < 4; j++)
                acc[i][j] = __builtin_amdgcn_mfma_f32_16x16x32_bf16(af[i], bfr[j], acc[i][j], 0, 0, 0);
    }

#pragma unroll
    for (int i = 0; i < 4; i++) {
        int mbase = bm * 128 + wr * 64 + i * 16 + quad * 4;
#pragma unroll
        for (int j = 0; j < 4; j++) {
            int n = bn * 128 + wc * 64 + j * 16 + l16;
            float bv = bias[n];
#pragma unroll
            for (int r = 0; r < 4; r++) {
                int m = mbase + r;
                if (m < M) {
                    float v = acc[i][j][r] + bv;
                    float g = 0.5f * v * (1.f + erff(v * 0.70710678118654752f));
                    C[(long)m * 4096 + n] = (bf16)g;
                }
            }
        }
    }
}

// ---------------- MoE GEMM2 (batched, split-K x4, scatter atomicAdd epilogue) ----------------
__global__ __launch_bounds__(256)
void gemm_moe2(const bf16* __restrict__ Hp, const bf16* __restrict__ ew2t,
               const float* __restrict__ eb2, float* __restrict__ moe_out,
               const int* __restrict__ counts, const int* __restrict__ bases,
               const int* __restrict__ tok, const float* __restrict__ combine) {
    const int e = blockIdx.z;
    const int M = counts[e];
    const int ks = blockIdx.y & 3;          // K-split slice
    const int bm = blockIdx.y >> 2;
    const int bn = blockIdx.x;
    if (bm * 128 >= M) return;
    const bf16* A = Hp + (long)bases[e] * 4096 + ks * 1024;
    const bf16* B = ew2t + (long)e * 4194304 + ks * 1024;
    const float* bias = eb2 + e * 1024;
    const int* etok = tok + e * 4096;

    __shared__ alignas(16) bf16 sA[128 * 32];
    __shared__ alignas(16) bf16 sB[128 * 32];
    const int tid  = threadIdx.x;
    const int lane = tid & 63, wave = tid >> 6;
    const int quad = lane >> 4, l16 = lane & 15;
    const int wr = wave >> 1, wc = wave & 1;
    const int sr = tid >> 2;
    const int sc = (tid & 3) * 8;

    int arow0 = min(bm * 128 + sr, M - 1);
    int arow1 = min(bm * 128 + sr + 64, M - 1);
    int brow0 = bn * 128 + sr;
    const bf16* pA0 = A + (long)arow0 * 4096 + sc;
    const bf16* pA1 = A + (long)arow1 * 4096 + sc;
    const bf16* pB0 = B + (long)brow0 * 4096 + sc;
    const bf16* pB1 = B + (long)(brow0 + 64) * 4096 + sc;
    const int wo = wave << 9;

    f32x4 acc[4][4];
#pragma unroll
    for (int i = 0; i < 4; i++)
#pragma unroll
        for (int j = 0; j < 4; j++) acc[i][j] = (f32x4){0.f, 0.f, 0.f, 0.f};

    for (int k0 = 0; k0 < 1024; k0 += 32) {
        __syncthreads();
        ld16(sA + wo,        pA0 + k0);
        ld16(sA + 2048 + wo, pA1 + k0);
        ld16(sB + wo,        pB0 + k0);
        ld16(sB + 2048 + wo, pB1 + k0);
        __syncthreads();
        bf16x8 af[4], bfr[4];
#pragma unroll
        for (int i = 0; i < 4; i++)
            af[i] = *(const bf16x8*)&sA[(wr * 64 + i * 16 + l16) * 32 + quad * 8];
#pragma unroll
        for (int j = 0; j < 4; j++)
            bfr[j] = *(const bf16x8*)&sB[(wc * 64 + j * 16 + l16) * 32 + quad * 8];
#pragma unroll
        for (int i = 0; i < 4; i++)
#pragma unroll
            for (int j = 0; j < 4; j++)
                acc[i][j] = __builtin_amdgcn_mfma_f32_16x16x32_bf16(af[i], bfr[j], acc[i][j], 0, 0, 0);
    }

#pragma unroll
    for (int i = 0; i < 4; i++) {
        int mbase = bm * 128 + wr * 64 + i * 16 + quad * 4;
#pragma unroll
        for (int j = 0; j < 4; j++) {
            int n = bn * 128 + wc * 64 + j * 16 + l16;
            float bv = (ks == 0) ? bias[n] : 0.f;
#pragma unroll
            for (int r = 0; r < 4; r++) {
                int m = mbase + r;
                if (m < M) {
                    int t = etok[m];
                    float s = combine[t * 8 + e];
                    atomicAdd(&moe_out[(long)t * 1024 + n], s * (acc[i][j][r] + bv));
                }
            }
        }
    }
}

// ---------------- per-slice V transpose ----------------
__global__ __launch_bounds__(256) void k_vsplit(const bf16* __restrict__ VH_h,
                                                const bf16* __restrict__ VH_l,
                                                bf16* __restrict__ VT_h,
                                                bf16* __restrict__ VT_l) {
    __shared__ bf16 th[64][65];
    __shared__ bf16 tl[64][65];
    int s = blockIdx.y, q0 = blockIdx.x * 64;
    int b = s >> 4, h = s & 15;
    long ibase = ((long)(b * 1024 + q0)) * 1024 + h * 64;
    for (int i = threadIdx.x; i < 4096; i += 256) {
        int q = i >> 6, d = i & 63;
        th[q][d] = VH_h[ibase + (long)q * 1024 + d];
        tl[q][d] = VH_l[ibase + (long)q * 1024 + d];
    }
    __syncthreads();
    long obase = (long)s * 65536 + q0;
    for (int i = threadIdx.x; i < 4096; i += 256) {
        int d = i >> 6, q = i & 63;
        VT_h[obase + (long)d * 1024 + q] = th[q][d];
        VT_l[obase + (long)d * 1024 + q] = tl[q][d];
    }
}

// ---------------- O reassembly ----------------
__global__ __launch_bounds__(256) void k_ocopy(const bf16* __restrict__ Op_h,
                                               const bf16* __restrict__ Op_l,
                                               bf16* __restrict__ O_h,
                                               bf16* __restrict__ O_l) {
    int t = blockIdx.x * 4 + (threadIdx.x >> 6);
    int lane = threadIdx.x & 63;
    int b = t >> 10, q = t & 1023;
    int h = lane >> 2, dd = (lane & 3) * 16;
    long src = ((long)(b * 16 + h)) * 65536 + (long)q * 64 + dd;
    long dst = (long)t * 1024 + h * 64 + dd;
    *(bf16x8*)(O_h + dst)     = *(const bf16x8*)(Op_h + src);
    *(bf16x8*)(O_h + dst + 8) = *(const bf16x8*)(Op_h + src + 8);
    *(bf16x8*)(O_l + dst)     = *(const bf16x8*)(Op_l + src);
    *(bf16x8*)(O_l + dst + 8) = *(const bf16x8*)(Op_l + src + 8);
}

// ---------------- gather expert rows (packed) ----------------
__global__ __launch_bounds__(256) void k_gather(const bf16* __restrict__ Xb,
                                                const int* __restrict__ tok,
                                                const int* __restrict__ counts,
                                                const int* __restrict__ bases,
                                                bf16* __restrict__ Ae) {
    int e = blockIdx.y;
    int cnt = counts[e];
    long base = bases[e];
    for (int i = blockIdx.x; i < cnt; i += gridDim.x) {
        int t = tok[e * 4096 + i];
        const bf16x4* src = (const bf16x4*)(Xb + (long)t * 1024);
        bf16x4* dst = (bf16x4*)(Ae + (base + i) * 1024);
        dst[threadIdx.x] = src[threadIdx.x];
    }
}

// ---------------- in-place softmax on split rows ----------------
__global__ __launch_bounds__(256) void k_softmax_ip(bf16* __restrict__ Sh,
                                                    bf16* __restrict__ Sl) {
    int row = blockIdx.x * 4 + (threadIdx.x >> 6);
    int lane = threadIdx.x & 63;
    long o = (long)row * 1024 + lane * 16;
    bf16x8 h0 = *(const bf16x8*)(Sh + o), h1 = *(const bf16x8*)(Sh + o + 8);
    bf16x8 l0 = *(const bf16x8*)(Sl + o), l1 = *(const bf16x8*)(Sl + o + 8);
    float v[16];
#pragma unroll
    for (int i = 0; i < 8; i++) {
        v[i] = (float)h0[i] + (float)l0[i];
        v[8 + i] = (float)h1[i] + (float)l1[i];
    }
    float mx = v[0];
#pragma unroll
    for (int i = 1; i < 16; i++) mx = fmaxf(mx, v[i]);
#pragma unroll
    for (int of = 32; of >= 1; of >>= 1) mx = fmaxf(mx, __shfl_xor(mx, of));
    float s = 0.f;
#pragma unroll
    for (int i = 0; i < 16; i++) { v[i] = expf(v[i] - mx); s += v[i]; }
#pragma unroll
    for (int of = 32; of >= 1; of >>= 1) s += __shfl_xor(s, of);
    float inv = 1.f / s;
#pragma unroll
    for (int i = 0; i < 8; i++) {
        float a = v[i] * inv;
        h0[i] = (bf16)a; l0[i] = (bf16)(a - (float)h0[i]);
        float b = v[8 + i] * inv;
        h1[i] = (bf16)b; l1[i] = (bf16)(b - (float)h1[i]);
    }
    *(bf16x8*)(Sh + o) = h0;  *(bf16x8*)(Sh + o + 8) = h1;
    *(bf16x8*)(Sl + o) = l0;  *(bf16x8*)(Sl + o + 8) = l1;
}

// ---------------- layernorm ----------------
__global__ __launch_bounds__(256) void k_ln(const float* __restrict__ xin,
                                            const float* __restrict__ resid,
                                            const float* __restrict__ g,
                                            const float* __restrict__ bb,
                                            float* __restrict__ outf,
                                            bf16* __restrict__ outb) {
    int row = blockIdx.x * 4 + (threadIdx.x >> 6);
    int lane = threadIdx.x & 63;
    long base = (long)row * 1024 + lane * 16;
    float v[16];
#pragma unroll
    for (int i = 0; i < 16; i += 4) {
        f32x4 a = *(const f32x4*)(xin + base + i);
        if (resid) { f32x4 r4 = *(const f32x4*)(resid + base + i); a += r4; }
        v[i] = a[0]; v[i + 1] = a[1]; v[i + 2] = a[2]; v[i + 3] = a[3];
    }
    float s = 0.f;
#pragma unroll
    for (int i = 0; i < 16; i++) s += v[i];
#pragma unroll
    for (int o = 32; o >= 1; o >>= 1) s += __shfl_xor(s, o);
    float mean = s * (1.f / 1024.f);
    float vs = 0.f;
#pragma unroll
    for (int i = 0; i < 16; i++) { float d = v[i] - mean; vs += d * d; }
#pragma unroll
    for (int o = 32; o >= 1; o >>= 1) vs += __shfl_xor(vs, o);
    float inv = 1.f / sqrtf(vs * (1.f / 1024.f) + 1e-5f);
    const float* gp = g + lane * 16;
    const float* bp = bb + lane * 16;
#pragma unroll
    for (int i = 0; i < 16; i++) {
        float o = (v[i] - mean) * inv * gp[i] + bp[i];
        if (outf) outf[base + i] = o;
        if (outb) outb[base + i] = (bf16)o;
    }
}

// ---------------- gating (no routing atomics) ----------------
__global__ __launch_bounds__(256) void k_gate(const float* __restrict__ X,
                                              const float* __restrict__ Wg,
                                              float* __restrict__ combine,
                                              float* __restrict__ partials) {
    __shared__ float sm[16];
    if (threadIdx.x < 16) sm[threadIdx.x] = 0.f;
    __syncthreads();
    int t = blockIdx.x * 4 + (threadIdx.x >> 6);
    int lane = threadIdx.x & 63;
    const float* x = X + (long)t * 1024;
    float acc[8] = {0.f, 0.f, 0.f, 0.f, 0.f, 0.f, 0.f, 0.f};
    for (int i = lane; i < 1024; i += 64) {
        float xv = x[i];
        const float* w = Wg + i * 8;
#pragma unroll
        for (int e = 0; e < 8; e++) acc[e] += xv * w[e];
    }
#pragma unroll
    for (int e = 0; e < 8; e++)
#pragma unroll
        for (int o = 32; o >= 1; o >>= 1) acc[e] += __shfl_xor(acc[e], o);
    if (lane == 0) {
        float mx = acc[0];
#pragma unroll
        for (int e = 1; e < 8; e++) mx = fmaxf(mx, acc[e]);
        float p[8], s = 0.f;
#pragma unroll
        for (int e = 0; e < 8; e++) { p[e] = expf(acc[e] - mx); s += p[e]; }
        float invs = 1.f / s;
#pragma unroll
        for (int e = 0; e < 8; e++) p[e] *= invs;
        float b1 = -1.f, b2 = -1.f, b3 = -1.f; int i1 = 0, i2 = 0, i3 = 0;
#pragma unroll
        for (int e = 0; e < 8; e++) {
            float pe = p[e];
            if (pe > b1)      { b3 = b2; i3 = i2; b2 = b1; i2 = i1; b1 = pe; i1 = e; }
            else if (pe > b2) { b3 = b2; i3 = i2; b2 = pe; i2 = e; }
            else if (pe > b3) { b3 = pe; i3 = e; }
        }
        float c[8] = {0.f, 0.f, 0.f, 0.f, 0.f, 0.f, 0.f, 0.f};
        c[i1] = b1;
        if (b2 >= THRESH_C) c[i2] = b2;
        if (b3 >= THRESH_C) c[i3] = b3;
        float* co = combine + (long)t * 8;
#pragma unroll
        for (int e = 0; e < 8; e++) co[e] = c[e];
#pragma unroll
        for (int e = 0; e < 8; e++) {
            atomicAdd(&sm[e], p[e]);
            if (c[e] > 0.f) atomicAdd(&sm[8 + e], 1.f);
        }
    }
    __syncthreads();
    if (threadIdx.x < 16) partials[(long)blockIdx.x * 16 + threadIdx.x] = sm[threadIdx.x];
}

// ---------------- deterministic routing (single block, prefix sums) ----------------
__global__ __launch_bounds__(256) void k_route(const float* __restrict__ combine,
                                               int* __restrict__ counts,
                                               int* __restrict__ bases,
                                               int* __restrict__ tok) {
    __shared__ int scan[256];
    __shared__ int ebase;
    int tid = threadIdx.x;
    if (tid == 0) ebase = 0;
    __syncthreads();
    for (int e = 0; e < 8; e++) {
        int pred[16]; int cnt = 0;
#pragma unroll
        for (int j = 0; j < 16; j++) {
            int t = tid * 16 + j;
            pred[j] = combine[t * 8 + e] > 0.f ? 1 : 0;
            cnt += pred[j];
        }
        scan[tid] = cnt;
        __syncthreads();
        for (int off = 1; off < 256; off <<= 1) {
            int v = (tid >= off) ? scan[tid - off] : 0;
            __syncthreads();
            scan[tid] += v;
            __syncthreads();
        }
        int o = e * 4096 + scan[tid] - cnt;
        int total = scan[255];
#pragma unroll
        for (int j = 0; j < 16; j++) {
            if (pred[j]) tok[o++] = tid * 16 + j;
        }
        if (tid == 0) { counts[e] = total; bases[e] = ebase; ebase += total; }
        __syncthreads();
    }
}

// ---------------- aux reduce ----------------
__global__ __launch_bounds__(256) void k_aux(const float* __restrict__ partials, int nblocks,
                                             float* __restrict__ auxout) {
    __shared__ float red[256];
    int tid = threadIdx.x;
    int e = tid & 15, grp = tid >> 4;
    float s = 0.f;
    for (int b = grp; b < nblocks; b += 16) s += partials[(long)b * 16 + e];
    red[tid] = s;
    __syncthreads();
    if (grp == 0) {
        float tot = 0.f;
        for (int g2 = 0; g2 < 16; g2++) tot += red[g2 * 16 + e];
        red[tid] = tot;
    }
    __syncthreads();
    if (tid == 0) {
        float s2 = 0.f;
        for (int e2 = 0; e2 < 8; e2++)
            s2 += (red[8 + e2] * (1.f / 4096.f)) * (red[e2] * (1.f / 4096.f));
        auxout[0] = COEF_C * 8.f * s2;
    }
}

// ---------------- host ----------------
extern "C" void kernel_launch(void* const* d_in, const int* in_sizes, int n_in,
                              void* d_out, int out_size, void* d_ws, size_t ws_size,
                              hipStream_t stream) {
    const float* query     = (const float*)d_in[0];
    const float* key_value = (const float*)d_in[1];
    const float* Wq   = (const float*)d_in[2];
    const float* bq   = (const float*)d_in[3];
    const float* Wk   = (const float*)d_in[4];
    const float* bk   = (const float*)d_in[5];
    const float* Wv   = (const float*)d_in[6];
    const float* bv   = (const float*)d_in[7];
    const float* W_in = (const float*)d_in[8];
    const float* b_in = (const float*)d_in[9];
    const float* W_out = (const float*)d_in[10];
    const float* b_out = (const float*)d_in[11];
    const float* Wa   = (const float*)d_in[12];
    const float* ba   = (const float*)d_in[13];
    const float* ln1_g = (const float*)d_in[14];
    const float* ln1_b = (const float*)d_in[15];
    const float* Wg   = (const float*)d_in[16];
    const float* ew1  = (const float*)d_in[17];
    const float* eb1  = (const float*)d_in[18];
    const float* ew2  = (const float*)d_in[19];
    const float* eb2  = (const float*)d_in[20];
    const float* ln2_g = (const float*)d_in[21];
    const float* ln2_b = (const float*)d_in[22];

    const size_t MBY = 1ull << 20;
    const long MB1 = 1024L * 1024L;
    char* ws = (char*)d_ws;

    // phase-aliased workspace map (peak ~345 MB)
    bf16* Sh   = (bf16*)(ws + 0 * MBY);      // attn: 64MB (32 slices split-hi)
    bf16* Sl   = (bf16*)(ws + 64 * MBY);     // attn: 64MB
    bf16* ew1t = (bf16*)(ws + 0 * MBY);      // MoE phase
    bf16* ew2t = (bf16*)(ws + 64 * MBY);
    // prep region [128,192): contiguous slice layouts for merged launches
    bf16* WAll_h = (bf16*)(ws + 128 * MBY);  // 8MB: Win(3) + Wa slices
    bf16* WAll_l = (bf16*)(ws + 136 * MBY);  // 8MB
    bf16* WT_h   = (bf16*)(ws + 144 * MBY);  // 8MB: WqT,WkT,WvT,WoT slices
    bf16* WT_l   = (bf16*)(ws + 152 * MBY);  // 8MB
    bf16* Xq_h  = (bf16*)(ws + 160 * MBY), *Xq_l  = (bf16*)(ws + 168 * MBY);
    bf16* Xkv_h = (bf16*)(ws + 176 * MBY), *Xkv_l = (bf16*)(ws + 184 * MBY);
    // attn-phase aliases
    bf16* O_h  = (bf16*)(ws + 160 * MBY), *O_l  = (bf16*)(ws + 168 * MBY);  // over dead Xq
    bf16* QHp_h = (bf16*)(ws + 192 * MBY), *QHp_l = (bf16*)(ws + 200 * MBY);
    bf16* KHp_h = (bf16*)(ws + 208 * MBY), *KHp_l = (bf16*)(ws + 216 * MBY);
    bf16* VH_h  = (bf16*)(ws + 224 * MBY), *VH_l  = (bf16*)(ws + 232 * MBY);
    bf16* VTp_h = (bf16*)(ws + 240 * MBY), *VTp_l = (bf16*)(ws + 248 * MBY);
    bf16* Op_h  = (bf16*)(ws + 256 * MBY), *Op_l  = (bf16*)(ws + 264 * MBY);
    float* Xf   = (float*)(ws + 256 * MBY);   // over dead Op
    float* Af   = (float*)(ws + 272 * MBY);
    // MoE phase
    bf16* Ae      = (bf16*)(ws + 128 * MBY);  // packed, worst 24MB
    bf16* Hp      = (bf16*)(ws + 152 * MBY);  // packed, worst 96MB
    float* moe_out = (float*)(ws + 272 * MBY);// over dead Af
    bf16* Xb   = (bf16*)(ws + 320 * MBY);
    bf16* Weff_h = (bf16*)(ws + 328 * MBY);   // 8MB: Weq,Wek,Wev,Woa slices
    bf16* Weff_l = (bf16*)(ws + 336 * MBY);   // 8MB
    float* combine  = (float*)(ws + 344 * MBY);
    float* partials = (float*)(ws + 344 * MBY + 128 * 1024);
    float* beff     = (float*)(ws + 344 * MBY + 192 * 1024);  // 4x1024 (slot3 = b_oa)
    int*   counts   = (int*)  (ws + 344 * MBY + 212 * 1024);
    int*   bases    = (int*)  (ws + 344 * MBY + 213 * 1024);
    int*   tok      = (int*)  (ws + 344 * MBY + 214 * 1024);

    dim3 blk(256);

    // ---- prep: conversions + splits (merged) ----
    k_f32_to_split<<<4096, blk, 0, stream>>>(query, Xq_h, Xq_l, 4L * MB1);
    k_f32_to_split<<<4096, blk, 0, stream>>>(key_value, Xkv_h, Xkv_l, 4L * MB1);
    k_f32_to_split<<<3072, blk, 0, stream>>>(W_in, WAll_h, WAll_l, 3L * MB1);
    k_f32_to_split<<<1024, blk, 0, stream>>>(Wa, WAll_h + 3 * MB1, WAll_l + 3 * MB1, MB1);
    k_transpose4_split<<<dim3(16, 16, 4), blk, 0, stream>>>(Wq, Wk, Wv, W_out, WT_h, WT_l);
    k_bias_fold4<<<dim3(256, 4), blk, 0, stream>>>(W_in, Wa, bq, bk, bv, b_out, b_in, ba, beff);

    // ---- weight folds: one z=4 launch ----
    gemm_hp<HP_SPLIT><<<dim3(8, 8, 4), blk, 0, stream>>>(
        WAll_h, WAll_l, 1024, MB1, WT_h, WT_l, 1024, MB1,
        Weff_h, Weff_l, 1024, MB1, nullptr, 1.f, 1024, 1024, 1024);

    // ---- projections: Q/K to head-split layout, V to token layout ----
    dim3 gP(8, 32, 1);
    gemm_hp<HP_SPLIT_HEADS><<<gP, blk, 0, stream>>>(Xq_h, Xq_l, 1024, 0, Weff_h, Weff_l, 1024, 0,
                                                    QHp_h, QHp_l, 0, 0, beff, 1.f, 4096, 1024, 1024);
    gemm_hp<HP_SPLIT_HEADS><<<gP, blk, 0, stream>>>(Xkv_h, Xkv_l, 1024, 0, Weff_h + MB1, Weff_l + MB1, 1024, 0,
                                                    KHp_h, KHp_l, 0, 0, beff + 1024, 1.f, 4096, 1024, 1024);
    gemm_hp<HP_SPLIT><<<gP, blk, 0, stream>>>(Xkv_h, Xkv_l, 1024, 0, Weff_h + 2 * MB1, Weff_l + 2 * MB1, 1024, 0,
                                              VH_h, VH_l, 1024, 0, beff + 2048, 1.f, 4096, 1024, 1024);
    k_vsplit<<<dim3(16, 64), blk, 0, stream>>>(VH_h, VH_l, VTp_h, VTp_l);

    // ---- attention: 2 halves of 32 (b,h) slices ----
    for (int half = 0; half < 2; half++) {
        long so = (long)half * 32 * 65536;
        gemm_hp<HP_SPLIT><<<dim3(8, 8, 32), blk, 0, stream>>>(
            QHp_h + so, QHp_l + so, 64, 65536,
            KHp_h + so, KHp_l + so, 64, 65536,
            Sh, Sl, 1024, MB1, nullptr, 0.125f, 1024, 1024, 64);
        k_softmax_ip<<<8192, blk, 0, stream>>>(Sh, Sl);
        gemm_pv<<<dim3(8, 32), blk, 0, stream>>>(Sh, Sl, VTp_h + so, VTp_l + so,
                                                 Op_h + so, Op_l + so);
    }
    k_ocopy<<<1024, blk, 0, stream>>>(Op_h, Op_l, O_h, O_l);

    // ---- out-proj+adapter (folded) + LN1 + gate + route ----
    gemm_hp<HP_F32><<<gP, blk, 0, stream>>>(O_h, O_l, 1024, 0, Weff_h + 3 * MB1, Weff_l + 3 * MB1, 1024, 0,
                                            Af, nullptr, 1024, 0, beff + 3072, 1.f, 4096, 1024, 1024);
    k_ln<<<1024, blk, 0, stream>>>(Af, query, ln1_g, ln1_b, Xf, Xb);
    k_gate<<<1024, blk, 0, stream>>>(Xf, Wg, combine, partials);
    k_route<<<1, blk, 0, stream>>>(combine, counts, bases, tok);
    k_gather<<<dim3(512, 8), blk, 0, stream>>>(Xb, tok, counts, bases, Ae);

    // ---- expert weight transposes ----
    k_transpose_ew<<<dim3(64, 16, 8), blk, 0, stream>>>(ew1, ew1t, 1024, 4096);
    k_transpose_ew<<<dim3(16, 64, 8), blk, 0, stream>>>(ew2, ew2t, 4096, 1024);

    // ---- batched routed MoE (GEMM2 split-K x4) ----
    hipMemsetAsync(moe_out, 0, (long)4096 * 1024 * 4, stream);
    gemm_moe1<<<dim3(32, 32, 8), blk, 0, stream>>>(Ae, ew1t, eb1, Hp, counts, bases);
    gemm_moe2<<<dim3(8, 128, 8), blk, 0, stream>>>(Hp, ew2t, eb2, moe_out, counts, bases, tok, combine);

    // ---- LN2 + aux ----
    k_ln<<<1024, blk, 0, stream>>>(moe_out, Xf, ln2_g, ln2_b, (float*)d_out, nullptr);
    k_aux<<<1, blk, 0, stream>>>(partials, 1024, (float*)d_out + (out_size - 1));
}